// Round 8
// baseline (236.494 us; speedup 1.0000x reference)
//
#include <hip/hip_runtime.h>
#include <stdint.h>

// B=4, T=1024, D=1024, H=16, DH=64. fp32 in/out, absmax thr 0.1.
// R16 vs R15: kill the 8-way LDS bank conflicts in the GEMMs.
// gemm_qkv showed SQ_LDS_BANK_CONFLICT=3.1M/dispatch, MfmaUtil 24.8%.
// Read As[row*32 + quad*8]: bank = (lm*16+quad*4)%32 -> 8 lanes share a
// 4-bank group (8-way; free min is 2). Fix (guide rule #21, both-sides):
// store K-chunk c of row r at slot c ^ ((r&15)>>1 & 3). gld_lds dest stays
// linear; the per-lane GLOBAL source is pre-permuted
// (acol = ((lane&3) ^ ((lane>>3)&3))<<3); reads use slot quad^((lm>>1)&3).
// 16 lanes/quad now cover each 4-bank group exactly 2x = conflict-free.
// Applied to gemm_qkv + both gemm_ffn. Everything else = R15.

#define B_  4
#define T_  1024
#define D_  1024
#define H_  16
#define DH_ 64

typedef __attribute__((ext_vector_type(8))) short short8;
typedef __attribute__((ext_vector_type(4))) float floatx4;
typedef __attribute__((ext_vector_type(4))) _Float16 half4;

__device__ __forceinline__ unsigned short f2bf(float f) {
  union { float f; uint32_t u; } a; a.f = f;
  uint32_t r = a.u + 0x7FFFu + ((a.u >> 16) & 1u);
  return (unsigned short)(r >> 16);
}
__device__ __forceinline__ float bf2f(unsigned short u) {
  union { uint32_t u; float f; } a; a.u = ((uint32_t)u) << 16;
  return a.f;
}

#define GLD_LDS16(g, l) __builtin_amdgcn_global_load_lds( \
    (const __attribute__((address_space(1))) unsigned int*)(g), \
    (__attribute__((address_space(3))) unsigned int*)(l), 16, 0, 0)

// ---------------------------------------------- prep: cast x + transpose W
__global__ __launch_bounds__(256)
void prep_kernel(const float4* __restrict__ x4, unsigned short* __restrict__ xb,
                 const float* __restrict__ w0, const float* __restrict__ w1,
                 const float* __restrict__ w2, const float* __restrict__ w3,
                 const float* __restrict__ w4, unsigned short* __restrict__ dst_all) {
  const int t = threadIdx.x;
  if (blockIdx.x < 1024) {
    int idx0 = blockIdx.x * 1024 + t;
#pragma unroll
    for (int c = 0; c < 4; ++c) {
      int idx = idx0 + c * 256;
      float4 v = x4[idx];
      union { uint2 u; unsigned short s[4]; } o;
      o.s[0] = f2bf(v.x); o.s[1] = f2bf(v.y); o.s[2] = f2bf(v.z); o.s[3] = f2bf(v.w);
      *(uint2*)&xb[(size_t)idx * 4] = o.u;
    }
    return;
  }
  const int b = blockIdx.x - 1024;
  const int z = b >> 8, ky = (b >> 4) & 15, nx = b & 15;
  const float* src = (z == 0) ? w0 : (z == 1) ? w1 : (z == 2) ? w2 : (z == 3) ? w3 : w4;
  unsigned short* dst = dst_all + (size_t)z * D_ * D_;
  __shared__ __align__(16) unsigned short tile[64 * 72];
  const int k0 = ky * 64, n0 = nx * 64;
#pragma unroll
  for (int c = 0; c < 4; ++c) {
    int idx = c * 256 + t;
    int r = idx >> 4, cc = (idx & 15) << 2;
    float4 v = *(const float4*)&src[(size_t)(k0 + r) * D_ + n0 + cc];
    tile[(cc + 0) * 72 + r] = f2bf(v.x);
    tile[(cc + 1) * 72 + r] = f2bf(v.y);
    tile[(cc + 2) * 72 + r] = f2bf(v.z);
    tile[(cc + 3) * 72 + r] = f2bf(v.w);
  }
  __syncthreads();
  int rr = t >> 2, ck = (t & 3) << 4;
  uint4 v0 = *(const uint4*)&tile[rr * 72 + ck];
  uint4 v1 = *(const uint4*)&tile[rr * 72 + ck + 8];
  *(uint4*)&dst[(size_t)(n0 + rr) * D_ + k0 + ck] = v0;
  *(uint4*)&dst[(size_t)(n0 + rr) * D_ + k0 + ck + 8] = v1;
}

// ------------------------------------------------------------------ QKV GEMM
__global__ __launch_bounds__(256, 2)
void gemm_qkv(const unsigned short* __restrict__ A,
              const unsigned short* __restrict__ Bt,
              unsigned short* __restrict__ oQ, unsigned short* __restrict__ oK,
              _Float16* __restrict__ oV) {
  const int K = 1024;
  __shared__ __align__(16) unsigned short As[128 * 32];
  __shared__ __align__(16) unsigned short Bs[128 * 32];
  __shared__ __align__(16) _Float16 Cs[2 * 64 * 136];
  const int t = threadIdx.x;
  const int lane = t & 63, w = t >> 6;
  const int quad = lane >> 4, lm = lane & 15;
  const int wm = w >> 1, wn = w & 1;
  const int m0 = blockIdx.y * 128, n0 = blockIdx.x * 128;
  // swizzled staging: lane stages row (lane>>2), LDS slot (lane&3);
  // global chunk = slot ^ ((row>>1)&3)  [row low 4 bits]
  const int arow = w * 32 + (lane >> 2);
  const int acol = (((lane & 3) ^ ((lane >> 3) & 3)) << 3);
  // swizzled read slot for this lane (same for A and B; key = (lm>>1)&3)
  const int rslot = (quad ^ ((lm >> 1) & 3)) * 8;

  floatx4 acc[4][4];
#pragma unroll
  for (int i = 0; i < 4; ++i)
#pragma unroll
    for (int j = 0; j < 4; ++j) acc[i][j] = (floatx4){0.f, 0.f, 0.f, 0.f};

  for (int kt = 0; kt < K; kt += 32) {
    const unsigned short* ga = A + (size_t)(m0 + arow) * K + kt + acol;
    const unsigned short* gb = Bt + (size_t)(n0 + arow) * K + kt + acol;
    GLD_LDS16(ga, &As[(w * 32) * 32]);
    GLD_LDS16(ga + (size_t)16 * K, &As[(w * 32 + 16) * 32]);
    GLD_LDS16(gb, &Bs[(w * 32) * 32]);
    GLD_LDS16(gb + (size_t)16 * K, &Bs[(w * 32 + 16) * 32]);
    __syncthreads();
    short8 a[4], b[4];
#pragma unroll
    for (int i = 0; i < 4; ++i) a[i] = *(const short8*)&As[(wm * 64 + i * 16 + lm) * 32 + rslot];
#pragma unroll
    for (int j = 0; j < 4; ++j) b[j] = *(const short8*)&Bs[(wn * 64 + j * 16 + lm) * 32 + rslot];
#pragma unroll
    for (int i = 0; i < 4; ++i)
#pragma unroll
      for (int j = 0; j < 4; ++j)
        acc[i][j] = __builtin_amdgcn_mfma_f32_16x16x32_bf16(a[i], b[j], acc[i][j], 0, 0, 0);
    __syncthreads();
  }

  if (n0 < 2048) {
    unsigned short* p = (n0 < 1024) ? oQ : oK;
    const float qscale = (n0 < 1024) ? 0.18033688f : 1.0f;   // 0.125*log2(e)
#pragma unroll
    for (int i = 0; i < 4; ++i) {
      int gmb = m0 + wm * 64 + i * 16 + quad * 4;
#pragma unroll
      for (int j = 0; j < 4; ++j) {
        int gn = n0 + wn * 64 + j * 16 + lm;
        int nn = gn & 1023, hh = nn >> 6, dd = nn & 63;
#pragma unroll
        for (int r = 0; r < 4; ++r) {
          int gm = gmb + r;
          int bb = gm >> 10, tt = gm & 1023;
          p[(((size_t)bb * H_ + hh) * T_ + tt) * DH_ + dd] = f2bf(acc[i][j][r] * qscale);
        }
      }
    }
  } else {
#pragma unroll
    for (int i = 0; i < 4; ++i) {
#pragma unroll
      for (int j = 0; j < 4; ++j) {
        int gn = n0 + wn * 64 + j * 16 + lm;
        int hd = (gn >> 6) & 1, dd = gn & 63;
        int kperm = quad * 32 + (wm * 4 + i) * 4;
        union { _Float16 h[4]; uint2 u; } pk;
#pragma unroll
        for (int r = 0; r < 4; ++r) pk.h[r] = (_Float16)acc[i][j][r];
        *(uint2*)&Cs[((size_t)(hd * 64 + dd)) * 136 + kperm] = pk.u;
      }
    }
    __syncthreads();
    const int row = t >> 1, half = t & 1;
    const int hd = row >> 6, dd = row & 63;
    const int hh = ((n0 & 1023) >> 6) + hd;
    const int bb = m0 >> 10, kbg = (m0 >> 7) & 7;
    const _Float16* srcp = &Cs[(size_t)(hd * 64 + dd) * 136 + half * 64];
    _Float16* dstp = oV + ((((size_t)bb * H_ + hh) * DH_ + dd) * 8 + kbg) * 128 + half * 64;
#pragma unroll
    for (int g = 0; g < 8; ++g)
      *(uint4*)(dstp + g * 8) = *(const uint4*)(srcp + g * 8);
  }
}

// ------------------------------------------------------------ FFN GEMM 64x128
// MODE 1: relu -> bf16.  MODE 2: plain -> bf16 (ffn buffer, read by ln_double).
template <int MODE>
__global__ __launch_bounds__(256, 2)
void gemm_ffn(const unsigned short* __restrict__ A,
              const unsigned short* __restrict__ Bt,
              unsigned short* __restrict__ oBf,
              const float* __restrict__ bias) {
  const int K = 1024, N = 1024;
  __shared__ __align__(16) unsigned short As[64 * 32];
  __shared__ __align__(16) unsigned short Bs[128 * 32];
  const int t = threadIdx.x;
  const int lane = t & 63, w = t >> 6;
  const int quad = lane >> 4, lm = lane & 15;
  const int wm = w >> 1, wn = w & 1;
  const int m0 = blockIdx.y * 64, n0 = blockIdx.x * 128;
  const int lrow = lane >> 2;
  const int lcol = (((lane & 3) ^ ((lane >> 3) & 3)) << 3);   // swizzled source
  const int rslot = (quad ^ ((lm >> 1) & 3)) * 8;             // swizzled read

  floatx4 acc[2][4];
#pragma unroll
  for (int i = 0; i < 2; ++i)
#pragma unroll
    for (int j = 0; j < 4; ++j) acc[i][j] = (floatx4){0.f, 0.f, 0.f, 0.f};

  for (int kt = 0; kt < K; kt += 32) {
    const unsigned short* ga = A + (size_t)(m0 + w * 16 + lrow) * K + kt + lcol;
    const unsigned short* gb = Bt + (size_t)(n0 + w * 32 + lrow) * K + kt + lcol;
    GLD_LDS16(ga, &As[(w * 16) * 32]);
    GLD_LDS16(gb, &Bs[(w * 32) * 32]);
    GLD_LDS16(gb + (size_t)16 * K, &Bs[(w * 32 + 16) * 32]);
    __syncthreads();
    short8 a[2], b[4];
#pragma unroll
    for (int i = 0; i < 2; ++i) a[i] = *(const short8*)&As[(wm * 32 + i * 16 + lm) * 32 + rslot];
#pragma unroll
    for (int j = 0; j < 4; ++j) b[j] = *(const short8*)&Bs[(wn * 64 + j * 16 + lm) * 32 + rslot];
#pragma unroll
    for (int i = 0; i < 2; ++i)
#pragma unroll
      for (int j = 0; j < 4; ++j)
        acc[i][j] = __builtin_amdgcn_mfma_f32_16x16x32_bf16(a[i], b[j], acc[i][j], 0, 0, 0);
    __syncthreads();
  }

#pragma unroll
  for (int i = 0; i < 2; ++i) {
    int gmb = m0 + wm * 32 + i * 16 + quad * 4;
#pragma unroll
    for (int j = 0; j < 4; ++j) {
      int gn = n0 + wn * 64 + j * 16 + lm;
      float bv = bias[gn];
#pragma unroll
      for (int r = 0; r < 4; ++r) {
        int gm = gmb + r;
        float v = acc[i][j][r] + bv;
        if (MODE == 1) v = fmaxf(v, 0.f);
        oBf[(size_t)gm * N + gn] = f2bf(v);
      }
    }
  }
}

// --------------------------------------------------------------- flash attn
// 512 blocks x 256 thr; R12 decode; K+V LDS double-buffered (R14).
__global__ __launch_bounds__(256)
void flash_attn(const unsigned short* __restrict__ Qb,
                const unsigned short* __restrict__ Kb,
                const _Float16* __restrict__ Vtg,
                const float* __restrict__ maskp,
                unsigned short* __restrict__ attn) {
  __shared__ __align__(16) unsigned short KLs[2][8192];  // 2 x 16 KB
  __shared__ __align__(16) _Float16      VLs[2][8192];   // 2 x 16 KB

  const int t = threadIdx.x;
  const int lane = t & 63, w = t >> 6;
  const int quad = lane >> 4, lm = lane & 15;

  const int bid = blockIdx.x;               // 0..511
  const int hi  = bid >> 8;                 // 0/1: co-residency half
  const int lo  = bid & 255;
  const int xcd = lo & 7;
  const int hgrp = (lo >> 3) & 7;
  const int qpair = lo >> 6;                // 0..3
  const int qb = hi ? (7 - qpair) : qpair;  // pair (p, 7-p) share a CU
  const int head = hgrp * 8 + xcd;          // 0..63; head%8 = XCD
  const int hh = head & 15, bb = head >> 4;
  const int q0 = qb << 7;

  const size_t headoff = ((size_t)bb * H_ + hh) * T_ * DH_;
  const unsigned short* Qh = Qb + headoff;
  const unsigned short* Kh = Kb + headoff;
  const _Float16* Vh = Vtg + headoff;   // k-shuffled [d][kb][quad][j][r]

  short8 qf[2][2];
#pragma unroll
  for (int qg = 0; qg < 2; ++qg)
#pragma unroll
    for (int ks = 0; ks < 2; ++ks)
      qf[qg][ks] = *(const short8*)(Qh + (size_t)(q0 + w * 32 + qg * 16 + lm) * 64 + ks * 32 + quad * 8);

  float lsum[2] = {0.f, 0.f};
  floatx4 acc[2][4];
#pragma unroll
  for (int qg = 0; qg < 2; ++qg)
#pragma unroll
    for (int j2 = 0; j2 < 4; ++j2) acc[qg][j2] = (floatx4){0.f, 0.f, 0.f, 0.f};

  const int qglob0 = q0 + w * 32 + lm;
  const bool excl1 = (qglob0 + 16 == 1023);   // row-1023 lane (qg=1 only)
  const float MSHIFT = 14426.950408f;          // 10000*log2(e)

  const int my_lo  = (qb == 7 && w == 3) ? 0 : qb;  // this wave's first kb
  const int blk_lo = (qb == 7) ? 0 : qb;            // block staging range

  // per-wave staging source addresses (slots s = w*4 .. w*4+3)
  const unsigned short* gk[4];
  const _Float16* gv[4];
#pragma unroll
  for (int i = 0; i < 4; ++i) {
    int s = w * 4 + i;
    gk[i] = Kh + (size_t)((s >> 1) * 16 + lm) * 64 + (s & 1) * 32 + quad * 8;
    gv[i] = Vh + ((size_t)((s >> 2) * 16 + lm) * 8) * 128 + quad * 32 + (s & 3) * 8;
  }

  // prologue: stage blk_lo into buffer 0
#pragma unroll
  for (int i = 0; i < 4; ++i) {
    int s = w * 4 + i;
    GLD_LDS16(gk[i] + (size_t)blk_lo * 8192, &KLs[0][s * 512]);
    GLD_LDS16(gv[i] + (size_t)blk_lo * 128,  &VLs[0][s * 512]);
  }

  int cur = 0;
  for (int kb = blk_lo; kb < 8; ++kb) {
    __syncthreads();   // drains vmcnt -> staged buffer [cur] is ready
    if (kb + 1 < 8) {
      int nxt = cur ^ 1;
#pragma unroll
      for (int i = 0; i < 4; ++i) {
        int s = w * 4 + i;
        GLD_LDS16(gk[i] + (size_t)(kb + 1) * 8192, &KLs[nxt][s * 512]);
        GLD_LDS16(gv[i] + (size_t)(kb + 1) * 128,  &VLs[nxt][s * 512]);
      }
    }
    if (kb >= my_lo) {
      const unsigned short* Kc = &KLs[cur][0];
      const _Float16* Vc = &VLs[cur][0];
      const int k0 = kb * 128;
      const bool need_mask = (kb <= qb);

      // prefetch j=0 fragments
      short8 kA = *(const short8*)&Kc[(0 * 64 + lane) * 8];
      short8 kB = *(const short8*)&Kc[(1 * 64 + lane) * 8];
      half4 vA0 = *(const half4*)&Vc[((0 * 4 + 0) * 64 + lane) * 8];
      half4 vA1 = *(const half4*)&Vc[((1 * 4 + 0) * 64 + lane) * 8];
      half4 vA2 = *(const half4*)&Vc[((2 * 4 + 0) * 64 + lane) * 8];
      half4 vA3 = *(const half4*)&Vc[((3 * 4 + 0) * 64 + lane) * 8];

#pragma unroll
      for (int j = 0; j < 8; ++j) {
        short8 nA, nB; half4 n0, n1, n2, n3;
        if (j < 7) {
          int jn = j + 1;
          nA = *(const short8*)&Kc[((jn * 2 + 0) * 64 + lane) * 8];
          nB = *(const short8*)&Kc[((jn * 2 + 1) * 64 + lane) * 8];
          n0 = *(const half4*)&Vc[((0 * 4 + (jn >> 1)) * 64 + lane) * 8 + (jn & 1) * 4];
          n1 = *(const half4*)&Vc[((1 * 4 + (jn >> 1)) * 64 + lane) * 8 + (jn & 1) * 4];
          n2 = *(const half4*)&Vc[((2 * 4 + (jn >> 1)) * 64 + lane) * 8 + (jn & 1) * 4];
          n3 = *(const half4*)&Vc[((3 * 4 + (jn >> 1)) * 64 + lane) * 8 + (jn & 1) * 4];
        }
        // S-MFMAs
        floatx4 st[2];
#pragma unroll
        for (int qg = 0; qg < 2; ++qg) {
          floatx4 z = (floatx4){0.f, 0.f, 0.f, 0.f};
          z = __builtin_amdgcn_mfma_f32_16x16x32_bf16(kA, qf[qg][0], z, 0, 0, 0);
          st[qg] = __builtin_amdgcn_mfma_f32_16x16x32_bf16(kB, qf[qg][1], z, 0, 0, 0);
        }
        // softmax j
        half4 pa[2];
#pragma unroll
        for (int qg = 0; qg < 2; ++qg) {
          const int qq = qglob0 + qg * 16;
          const bool skip = (qg == 1) && excl1;
#pragma unroll
          for (int r = 0; r < 4; ++r) {
            int kg = k0 + j * 16 + quad * 4 + r;
            float v = st[qg][r];
            if (need_mask && !skip && kg <= qq) v -= MSHIFT;
            float p = __builtin_amdgcn_exp2f(v);
            lsum[qg] += p;
            pa[qg][r] = (_Float16)p;
          }
        }
        // PV j
        acc[0][0] = __builtin_amdgcn_mfma_f32_16x16x16f16(pa[0], vA0, acc[0][0], 0, 0, 0);
        acc[1][0] = __builtin_amdgcn_mfma_f32_16x16x16f16(pa[1], vA0, acc[1][0], 0, 0, 0);
        acc[0][1] = __builtin_amdgcn_mfma_f32_16x16x16f16(pa[0], vA1, acc[0][1], 0, 0, 0);
        acc[1][1] = __builtin_amdgcn_mfma_f32_16x16x16f16(pa[1], vA1, acc[1][1], 0, 0, 0);
        acc[0][2] = __builtin_amdgcn_mfma_f32_16x16x16f16(pa[0], vA2, acc[0][2], 0, 0, 0);
        acc[1][2] = __builtin_amdgcn_mfma_f32_16x16x16f16(pa[1], vA2, acc[1][2], 0, 0, 0);
        acc[0][3] = __builtin_amdgcn_mfma_f32_16x16x16f16(pa[0], vA3, acc[0][3], 0, 0, 0);
        acc[1][3] = __builtin_amdgcn_mfma_f32_16x16x16f16(pa[1], vA3, acc[1][3], 0, 0, 0);
        // rotate prefetched fragments
        kA = nA; kB = nB; vA0 = n0; vA1 = n1; vA2 = n2; vA3 = n3;
      }
    }
    cur ^= 1;
  }

  // epilogue
#pragma unroll
  for (int qg = 0; qg < 2; ++qg) {
    float l = lsum[qg];
    l += __shfl_xor(l, 16);
    l += __shfl_xor(l, 32);
    float s = maskp[bb * T_ + qglob0 + qg * 16] / l;
#pragma unroll
    for (int r = 0; r < 4; ++r) {
      float bsc = __shfl(s, quad * 4 + r);
      int tq = q0 + w * 32 + qg * 16 + quad * 4 + r;
#pragma unroll
      for (int j2 = 0; j2 < 4; ++j2)
        attn[((size_t)(bb * T_ + tq)) * D_ + hh * 64 + j2 * 16 + lm] = f2bf(acc[qg][j2][r] * bsc);
    }
  }
}

// ------------------- LN(x + attn_bf16) -> h1 f32+bf16 (wave-per-row)
__global__ __launch_bounds__(256)
void ln_res_kernel(const float* __restrict__ xa, const unsigned short* __restrict__ attn,
                   const float* __restrict__ sc, const float* __restrict__ bi,
                   float* __restrict__ h, unsigned short* __restrict__ hb) {
  const int t = threadIdx.x;
  const int lane = t & 63, w = t >> 6;
  const int row = blockIdx.x * 4 + w;
  const size_t base = (size_t)row * D_ + lane * 16;

  float v[16];
  float s1 = 0.f, s2 = 0.f;
#pragma unroll
  for (int i = 0; i < 4; ++i) {
    float4 a = *(const float4*)&xa[base + i * 4];
    union { uint2 u; unsigned short s[4]; } au;
    au.u = *(const uint2*)&attn[base + i * 4];
    float x0 = a.x + bf2f(au.s[0]);
    float x1 = a.y + bf2f(au.s[1]);
    float x2 = a.z + bf2f(au.s[2]);
    float x3 = a.w + bf2f(au.s[3]);
    v[i * 4 + 0] = x0; v[i * 4 + 1] = x1; v[i * 4 + 2] = x2; v[i * 4 + 3] = x3;
    s1 += x0 + x1 + x2 + x3;
    s2 += x0 * x0 + x1 * x1 + x2 * x2 + x3 * x3;
  }
#pragma unroll
  for (int off = 1; off < 64; off <<= 1) {
    s1 += __shfl_xor(s1, off);
    s2 += __shfl_xor(s2, off);
  }
  float mean = s1 * (1.f / 1024.f);
  float var = s2 * (1.f / 1024.f) - mean * mean;
  float rstd = rsqrtf(var + 1e-5f);
#pragma unroll
  for (int i = 0; i < 4; ++i) {
    float4 sv = *(const float4*)&sc[lane * 16 + i * 4];
    float4 bv = *(const float4*)&bi[lane * 16 + i * 4];
    float o0 = (v[i * 4 + 0] - mean) * rstd * sv.x + bv.x;
    float o1 = (v[i * 4 + 1] - mean) * rstd * sv.y + bv.y;
    float o2 = (v[i * 4 + 2] - mean) * rstd * sv.z + bv.z;
    float o3 = (v[i * 4 + 3] - mean) * rstd * sv.w + bv.w;
    float4 ov = {o0, o1, o2, o3};
    *(float4*)&h[base + i * 4] = ov;
    union { uint2 u; unsigned short s[4]; } ob;
    ob.s[0] = f2bf(o0); ob.s[1] = f2bf(o1); ob.s[2] = f2bf(o2); ob.s[3] = f2bf(o3);
    *(uint2*)&hb[base + i * 4] = ob.u;
  }
}

// ---------------- out = LN(LN(h1+ffn_bf16,ln2),ln3) (wave-per-row)
__global__ __launch_bounds__(256)
void ln_double_kernel(const float* __restrict__ h1, const unsigned short* __restrict__ ffnb,
                      const float* __restrict__ s2c, const float* __restrict__ b2c,
                      const float* __restrict__ s3c, const float* __restrict__ b3c,
                      float* __restrict__ out) {
  const int t = threadIdx.x;
  const int lane = t & 63, w = t >> 6;
  const int row = blockIdx.x * 4 + w;
  const size_t base = (size_t)row * D_ + lane * 16;

  float v[16];
  float s1 = 0.f, s2 = 0.f;
#pragma unroll
  for (int i = 0; i < 4; ++i) {
    float4 a = *(const float4*)&h1[base + i * 4];
    union { uint2 u; unsigned short s[4]; } fu;
    fu.u = *(const uint2*)&ffnb[base + i * 4];
    float x0 = a.x + bf2f(fu.s[0]);
    float x1 = a.y + bf2f(fu.s[1]);
    float x2 = a.z + bf2f(fu.s[2]);
    float x3 = a.w + bf2f(fu.s[3]);
    v[i * 4 + 0] = x0; v[i * 4 + 1] = x1; v[i * 4 + 2] = x2; v[i * 4 + 3] = x3;
    s1 += x0 + x1 + x2 + x3;
    s2 += x0 * x0 + x1 * x1 + x2 * x2 + x3 * x3;
  }
#pragma unroll
  for (int off = 1; off < 64; off <<= 1) {
    s1 += __shfl_xor(s1, off);
    s2 += __shfl_xor(s2, off);
  }
  float mean = s1 * (1.f / 1024.f);
  float var = s2 * (1.f / 1024.f) - mean * mean;
  float rstd = rsqrtf(var + 1e-5f);

  float o[16];
  float u1 = 0.f, u2 = 0.f;
#pragma unroll
  for (int i = 0; i < 4; ++i) {
    float4 sv = *(const float4*)&s2c[lane * 16 + i * 4];
    float4 bv = *(const float4*)&b2c[lane * 16 + i * 4];
    float o0 = (v[i * 4 + 0] - mean) * rstd * sv.x + bv.x;
    float o1 = (v[i * 4 + 1] - mean) * rstd * sv.y + bv.y;
    float o2 = (v[i * 4 + 2] - mean) * rstd * sv.z + bv.z;
    float o3 = (v[i * 4 + 3] - mean) * rstd * sv.w + bv.w;
    o[i * 4 + 0] = o0; o[i * 4 + 1] = o1; o[i * 4 + 2] = o2; o[i * 4 + 3] = o3;
    u1 += o0 + o1 + o2 + o3;
    u2 += o0 * o0 + o1 * o1 + o2 * o2 + o3 * o3;
  }
#pragma unroll
  for (int off = 1; off < 64; off <<= 1) {
    u1 += __shfl_xor(u1, off);
    u2 += __shfl_xor(u2, off);
  }
  float mean2 = u1 * (1.f / 1024.f);
  float var2 = u2 * (1.f / 1024.f) - mean2 * mean2;
  float rstd2 = rsqrtf(var2 + 1e-5f);
#pragma unroll
  for (int i = 0; i < 4; ++i) {
    float4 sv = *(const float4*)&s3c[lane * 16 + i * 4];
    float4 bv = *(const float4*)&b3c[lane * 16 + i * 4];
    float4 fo;
    fo.x = (o[i * 4 + 0] - mean2) * rstd2 * sv.x + bv.x;
    fo.y = (o[i * 4 + 1] - mean2) * rstd2 * sv.y + bv.y;
    fo.z = (o[i * 4 + 2] - mean2) * rstd2 * sv.z + bv.z;
    fo.w = (o[i * 4 + 3] - mean2) * rstd2 * sv.w + bv.w;
    *(float4*)&out[base + i * 4] = fo;
  }
}

// ------------------------------------------------------------------ launch
extern "C" void kernel_launch(void* const* d_in, const int* in_sizes, int n_in,
                              void* d_out, int out_size, void* d_ws, size_t ws_size,
                              hipStream_t stream) {
  (void)in_sizes; (void)n_in; (void)out_size; (void)ws_size;
  const float* x   = (const float*)d_in[0];
  const float* msk = (const float*)d_in[1];
  const float* wq  = (const float*)d_in[2];
  const float* wk  = (const float*)d_in[3];
  const float* wv  = (const float*)d_in[4];
  const float* w1  = (const float*)d_in[5];
  const float* b1  = (const float*)d_in[6];
  const float* w2  = (const float*)d_in[7];
  const float* b2  = (const float*)d_in[8];
  const float* l1s = (const float*)d_in[9];
  const float* l1b = (const float*)d_in[10];
  const float* l2s = (const float*)d_in[11];
  const float* l2b = (const float*)d_in[12];
  const float* l3s = (const float*)d_in[13];
  const float* l3b = (const float*)d_in[14];
  float* outp = (float*)d_out;

  char* ws = (char*)d_ws;
  unsigned short* xb   = (unsigned short*)(ws);                       // 8 MB
  unsigned short* wt   = (unsigned short*)(ws + ((size_t)8  << 20));  // 10 MB
  unsigned short* Qb   = (unsigned short*)(ws + ((size_t)18 << 20));  // 8 MB [B,H,T,DH]
  unsigned short* Kb   = (unsigned short*)(ws + ((size_t)26 << 20));  // 8 MB
  _Float16*       Vtg  = (_Float16*)(ws + ((size_t)34 << 20));        // 8 MB k-shuffled V^T
  unsigned short* attn = (unsigned short*)(ws + ((size_t)42 << 20));  // 8 MB bf16 [B,T,D]
  float* h1            = (float*)(ws + ((size_t)50 << 20));           // 16 MB
  unsigned short* h1b  = (unsigned short*)(ws + ((size_t)18 << 20));  // reuse Qb
  unsigned short* gb   = (unsigned short*)(ws + ((size_t)26 << 20));  // reuse Kb
  unsigned short* ffnb = (unsigned short*)(ws + ((size_t)34 << 20));  // reuse Vtg (8 MB bf16)

  prep_kernel<<<1024 + 1280, 256, 0, stream>>>((const float4*)x, xb,
                                               wq, wk, wv, w1, w2, wt);
  gemm_qkv<<<dim3(24, 32), 256, 0, stream>>>(xb, wt, Qb, Kb, Vtg);
  flash_attn<<<512, 256, 0, stream>>>(Qb, Kb, Vtg, msk, attn);
  ln_res_kernel<<<1024, 256, 0, stream>>>(x, attn, l1s, l1b, h1, h1b);
  gemm_ffn<1><<<dim3(8, 64), 256, 0, stream>>>(h1b, wt + (size_t)3 * 1024 * 1024, gb, b1);
  gemm_ffn<2><<<dim3(8, 64), 256, 0, stream>>>(gb, wt + (size_t)4 * 1024 * 1024, ffnb, b2);
  ln_double_kernel<<<1024, 256, 0, stream>>>(h1, ffnb, l2s, l2b, l3s, l3b, outp);
}

// Round 9
// 228.033 us; speedup vs baseline: 1.0371x; 1.0371x over previous
//
#include <hip/hip_runtime.h>
#include <stdint.h>

// B=4, T=1024, D=1024, H=16, DH=64. fp32 in/out, absmax thr 0.1.
// R17 vs R16: barrier-drain amortization in the GEMMs. R16's conflict fix
// was correct but null -> conflicts weren't binding; qkv counters (Mfma 25
// + VALU 12 = 37% busy, occ 25% = 2 blocks/CU) say the cost is the vmcnt(0)
// drain at each of 32 barriers, under-hidden at 8 waves/CU.
//  - qkv: Cs (34KB, post-loop only) UNIONED over As+Bs (32KB): LDS 50->34.8KB
//    -> 3 blocks/CU co-resident (grid 768 = 3/CU exactly).
//  - qkv+ffn: BK 32->64: barriers 32->16, 2x MFMA per drain. 8-chunk rows,
//    XOR swizzle keyed lm&7 (store chunk (l&7)^((l>>3)&7) -> 128B coalesced
//    segments; read slot (ks*4+quad)^(lm&7) -> 2 lanes/bank = free).
//    ks-inner loop keeps fragment regs flat.
// flash/prep/LNs unchanged (R14/R15-proven).

#define B_  4
#define T_  1024
#define D_  1024
#define H_  16
#define DH_ 64

typedef __attribute__((ext_vector_type(8))) short short8;
typedef __attribute__((ext_vector_type(4))) float floatx4;
typedef __attribute__((ext_vector_type(4))) _Float16 half4;

__device__ __forceinline__ unsigned short f2bf(float f) {
  union { float f; uint32_t u; } a; a.f = f;
  uint32_t r = a.u + 0x7FFFu + ((a.u >> 16) & 1u);
  return (unsigned short)(r >> 16);
}
__device__ __forceinline__ float bf2f(unsigned short u) {
  union { uint32_t u; float f; } a; a.u = ((uint32_t)u) << 16;
  return a.f;
}

#define GLD_LDS16(g, l) __builtin_amdgcn_global_load_lds( \
    (const __attribute__((address_space(1))) unsigned int*)(g), \
    (__attribute__((address_space(3))) unsigned int*)(l), 16, 0, 0)

// ---------------------------------------------- prep: cast x + transpose W
__global__ __launch_bounds__(256)
void prep_kernel(const float4* __restrict__ x4, unsigned short* __restrict__ xb,
                 const float* __restrict__ w0, const float* __restrict__ w1,
                 const float* __restrict__ w2, const float* __restrict__ w3,
                 const float* __restrict__ w4, unsigned short* __restrict__ dst_all) {
  const int t = threadIdx.x;
  if (blockIdx.x < 1024) {
    int idx0 = blockIdx.x * 1024 + t;
#pragma unroll
    for (int c = 0; c < 4; ++c) {
      int idx = idx0 + c * 256;
      float4 v = x4[idx];
      union { uint2 u; unsigned short s[4]; } o;
      o.s[0] = f2bf(v.x); o.s[1] = f2bf(v.y); o.s[2] = f2bf(v.z); o.s[3] = f2bf(v.w);
      *(uint2*)&xb[(size_t)idx * 4] = o.u;
    }
    return;
  }
  const int b = blockIdx.x - 1024;
  const int z = b >> 8, ky = (b >> 4) & 15, nx = b & 15;
  const float* src = (z == 0) ? w0 : (z == 1) ? w1 : (z == 2) ? w2 : (z == 3) ? w3 : w4;
  unsigned short* dst = dst_all + (size_t)z * D_ * D_;
  __shared__ __align__(16) unsigned short tile[64 * 72];
  const int k0 = ky * 64, n0 = nx * 64;
#pragma unroll
  for (int c = 0; c < 4; ++c) {
    int idx = c * 256 + t;
    int r = idx >> 4, cc = (idx & 15) << 2;
    float4 v = *(const float4*)&src[(size_t)(k0 + r) * D_ + n0 + cc];
    tile[(cc + 0) * 72 + r] = f2bf(v.x);
    tile[(cc + 1) * 72 + r] = f2bf(v.y);
    tile[(cc + 2) * 72 + r] = f2bf(v.z);
    tile[(cc + 3) * 72 + r] = f2bf(v.w);
  }
  __syncthreads();
  int rr = t >> 2, ck = (t & 3) << 4;
  uint4 v0 = *(const uint4*)&tile[rr * 72 + ck];
  uint4 v1 = *(const uint4*)&tile[rr * 72 + ck + 8];
  *(uint4*)&dst[(size_t)(n0 + rr) * D_ + k0 + ck] = v0;
  *(uint4*)&dst[(size_t)(n0 + rr) * D_ + k0 + ck + 8] = v1;
}

// ------------------------------------------------------------------ QKV GEMM
// BK=64, Cs overlaid on As+Bs (LDS 34816B -> 3 blocks/CU at grid 768).
__global__ __launch_bounds__(256, 2)
void gemm_qkv(const unsigned short* __restrict__ A,
              const unsigned short* __restrict__ Bt,
              unsigned short* __restrict__ oQ, unsigned short* __restrict__ oK,
              _Float16* __restrict__ oV) {
  const int K = 1024;
  __shared__ __align__(16) unsigned char smem[34816];   // max(As+Bs=32KB, Cs=34KB)
  unsigned short* As = (unsigned short*)smem;           // 128x64 = 16KB
  unsigned short* Bs = (unsigned short*)(smem + 16384); // 128x64 = 16KB
  _Float16* Cs = (_Float16*)smem;                       // 2*64*136 (post-loop)
  const int t = threadIdx.x;
  const int lane = t & 63, w = t >> 6;
  const int quad = lane >> 4, lm = lane & 15;
  const int wm = w >> 1, wn = w & 1;
  const int m0 = blockIdx.y * 128, n0 = blockIdx.x * 128;
  // staging: lane l covers row i*8+(l>>3) of its wave's 32-row strip,
  // LDS slot (l&7); global chunk = (l&7)^((l>>3)&7)  [row key = row&7]
  const int srow = lane >> 3;
  const int scol = ((lane & 7) ^ srow) << 3;

  floatx4 acc[4][4];
#pragma unroll
  for (int i = 0; i < 4; ++i)
#pragma unroll
    for (int j = 0; j < 4; ++j) acc[i][j] = (floatx4){0.f, 0.f, 0.f, 0.f};

  for (int kt = 0; kt < K; kt += 64) {
#pragma unroll
    for (int i = 0; i < 4; ++i) {
      const unsigned short* ga = A + (size_t)(m0 + w * 32 + i * 8 + srow) * K + kt + scol;
      const unsigned short* gb = Bt + (size_t)(n0 + w * 32 + i * 8 + srow) * K + kt + scol;
      GLD_LDS16(ga, &As[w * 2048 + i * 512]);
      GLD_LDS16(gb, &Bs[w * 2048 + i * 512]);
    }
    __syncthreads();
#pragma unroll
    for (int ks = 0; ks < 2; ++ks) {
      const int rs = ((ks * 4 + quad) ^ (lm & 7)) << 3;   // read slot (free: 2/bank)
      short8 a[4], b[4];
#pragma unroll
      for (int i = 0; i < 4; ++i) a[i] = *(const short8*)&As[(wm * 64 + i * 16 + lm) * 64 + rs];
#pragma unroll
      for (int j = 0; j < 4; ++j) b[j] = *(const short8*)&Bs[(wn * 64 + j * 16 + lm) * 64 + rs];
#pragma unroll
      for (int i = 0; i < 4; ++i)
#pragma unroll
        for (int j = 0; j < 4; ++j)
          acc[i][j] = __builtin_amdgcn_mfma_f32_16x16x32_bf16(a[i], b[j], acc[i][j], 0, 0, 0);
    }
    __syncthreads();
  }

  if (n0 < 2048) {
    unsigned short* p = (n0 < 1024) ? oQ : oK;
    const float qscale = (n0 < 1024) ? 0.18033688f : 1.0f;   // 0.125*log2(e)
#pragma unroll
    for (int i = 0; i < 4; ++i) {
      int gmb = m0 + wm * 64 + i * 16 + quad * 4;
#pragma unroll
      for (int j = 0; j < 4; ++j) {
        int gn = n0 + wn * 64 + j * 16 + lm;
        int nn = gn & 1023, hh = nn >> 6, dd = nn & 63;
#pragma unroll
        for (int r = 0; r < 4; ++r) {
          int gm = gmb + r;
          int bb = gm >> 10, tt = gm & 1023;
          p[(((size_t)bb * H_ + hh) * T_ + tt) * DH_ + dd] = f2bf(acc[i][j][r] * qscale);
        }
      }
    }
  } else {
#pragma unroll
    for (int i = 0; i < 4; ++i) {
#pragma unroll
      for (int j = 0; j < 4; ++j) {
        int gn = n0 + wn * 64 + j * 16 + lm;
        int hd = (gn >> 6) & 1, dd = gn & 63;
        int kperm = quad * 32 + (wm * 4 + i) * 4;
        union { _Float16 h[4]; uint2 u; } pk;
#pragma unroll
        for (int r = 0; r < 4; ++r) pk.h[r] = (_Float16)acc[i][j][r];
        *(uint2*)&Cs[((size_t)(hd * 64 + dd)) * 136 + kperm] = pk.u;
      }
    }
    __syncthreads();
    const int row = t >> 1, half = t & 1;
    const int hd = row >> 6, dd = row & 63;
    const int hh = ((n0 & 1023) >> 6) + hd;
    const int bb = m0 >> 10, kbg = (m0 >> 7) & 7;
    const _Float16* srcp = &Cs[(size_t)(hd * 64 + dd) * 136 + half * 64];
    _Float16* dstp = oV + ((((size_t)bb * H_ + hh) * DH_ + dd) * 8 + kbg) * 128 + half * 64;
#pragma unroll
    for (int g = 0; g < 8; ++g)
      *(uint4*)(dstp + g * 8) = *(const uint4*)(srcp + g * 8);
  }
}

// ------------------------------------------------------------ FFN GEMM 64x128
// BK=64 (barriers 16). MODE 1: relu->bf16. MODE 2: plain->bf16.
template <int MODE>
__global__ __launch_bounds__(256, 2)
void gemm_ffn(const unsigned short* __restrict__ A,
              const unsigned short* __restrict__ Bt,
              unsigned short* __restrict__ oBf,
              const float* __restrict__ bias) {
  const int K = 1024, N = 1024;
  __shared__ __align__(16) unsigned short As[64 * 64];    // 8KB
  __shared__ __align__(16) unsigned short Bs[128 * 64];   // 16KB
  const int t = threadIdx.x;
  const int lane = t & 63, w = t >> 6;
  const int quad = lane >> 4, lm = lane & 15;
  const int wm = w >> 1, wn = w & 1;
  const int m0 = blockIdx.y * 64, n0 = blockIdx.x * 128;
  const int srow = lane >> 3;
  const int scol = ((lane & 7) ^ srow) << 3;

  floatx4 acc[2][4];
#pragma unroll
  for (int i = 0; i < 2; ++i)
#pragma unroll
    for (int j = 0; j < 4; ++j) acc[i][j] = (floatx4){0.f, 0.f, 0.f, 0.f};

  for (int kt = 0; kt < K; kt += 64) {
#pragma unroll
    for (int i = 0; i < 2; ++i) {
      const unsigned short* ga = A + (size_t)(m0 + w * 16 + i * 8 + srow) * K + kt + scol;
      GLD_LDS16(ga, &As[w * 1024 + i * 512]);
    }
#pragma unroll
    for (int i = 0; i < 4; ++i) {
      const unsigned short* gb = Bt + (size_t)(n0 + w * 32 + i * 8 + srow) * K + kt + scol;
      GLD_LDS16(gb, &Bs[w * 2048 + i * 512]);
    }
    __syncthreads();
#pragma unroll
    for (int ks = 0; ks < 2; ++ks) {
      const int rs = ((ks * 4 + quad) ^ (lm & 7)) << 3;
      short8 a[2], b[4];
#pragma unroll
      for (int i = 0; i < 2; ++i) a[i] = *(const short8*)&As[(wm * 32 + i * 16 + lm) * 64 + rs];
#pragma unroll
      for (int j = 0; j < 4; ++j) b[j] = *(const short8*)&Bs[(wn * 64 + j * 16 + lm) * 64 + rs];
#pragma unroll
      for (int i = 0; i < 2; ++i)
#pragma unroll
        for (int j = 0; j < 4; ++j)
          acc[i][j] = __builtin_amdgcn_mfma_f32_16x16x32_bf16(a[i], b[j], acc[i][j], 0, 0, 0);
    }
    __syncthreads();
  }

#pragma unroll
  for (int i = 0; i < 2; ++i) {
    int gmb = m0 + wm * 32 + i * 16 + quad * 4;
#pragma unroll
    for (int j = 0; j < 4; ++j) {
      int gn = n0 + wn * 64 + j * 16 + lm;
      float bv = bias[gn];
#pragma unroll
      for (int r = 0; r < 4; ++r) {
        int gm = gmb + r;
        float v = acc[i][j][r] + bv;
        if (MODE == 1) v = fmaxf(v, 0.f);
        oBf[(size_t)gm * N + gn] = f2bf(v);
      }
    }
  }
}

// --------------------------------------------------------------- flash attn
// 512 blocks x 256 thr; R12 decode; K+V LDS double-buffered (R14).
__global__ __launch_bounds__(256)
void flash_attn(const unsigned short* __restrict__ Qb,
                const unsigned short* __restrict__ Kb,
                const _Float16* __restrict__ Vtg,
                const float* __restrict__ maskp,
                unsigned short* __restrict__ attn) {
  __shared__ __align__(16) unsigned short KLs[2][8192];  // 2 x 16 KB
  __shared__ __align__(16) _Float16      VLs[2][8192];   // 2 x 16 KB

  const int t = threadIdx.x;
  const int lane = t & 63, w = t >> 6;
  const int quad = lane >> 4, lm = lane & 15;

  const int bid = blockIdx.x;               // 0..511
  const int hi  = bid >> 8;                 // 0/1: co-residency half
  const int lo  = bid & 255;
  const int xcd = lo & 7;
  const int hgrp = (lo >> 3) & 7;
  const int qpair = lo >> 6;                // 0..3
  const int qb = hi ? (7 - qpair) : qpair;  // pair (p, 7-p) share a CU
  const int head = hgrp * 8 + xcd;          // 0..63; head%8 = XCD
  const int hh = head & 15, bb = head >> 4;
  const int q0 = qb << 7;

  const size_t headoff = ((size_t)bb * H_ + hh) * T_ * DH_;
  const unsigned short* Qh = Qb + headoff;
  const unsigned short* Kh = Kb + headoff;
  const _Float16* Vh = Vtg + headoff;   // k-shuffled [d][kb][quad][j][r]

  short8 qf[2][2];
#pragma unroll
  for (int qg = 0; qg < 2; ++qg)
#pragma unroll
    for (int ks = 0; ks < 2; ++ks)
      qf[qg][ks] = *(const short8*)(Qh + (size_t)(q0 + w * 32 + qg * 16 + lm) * 64 + ks * 32 + quad * 8);

  float lsum[2] = {0.f, 0.f};
  floatx4 acc[2][4];
#pragma unroll
  for (int qg = 0; qg < 2; ++qg)
#pragma unroll
    for (int j2 = 0; j2 < 4; ++j2) acc[qg][j2] = (floatx4){0.f, 0.f, 0.f, 0.f};

  const int qglob0 = q0 + w * 32 + lm;
  const bool excl1 = (qglob0 + 16 == 1023);   // row-1023 lane (qg=1 only)
  const float MSHIFT = 14426.950408f;          // 10000*log2(e)

  const int my_lo  = (qb == 7 && w == 3) ? 0 : qb;  // this wave's first kb
  const int blk_lo = (qb == 7) ? 0 : qb;            // block staging range

  // per-wave staging source addresses (slots s = w*4 .. w*4+3)
  const unsigned short* gk[4];
  const _Float16* gv[4];
#pragma unroll
  for (int i = 0; i < 4; ++i) {
    int s = w * 4 + i;
    gk[i] = Kh + (size_t)((s >> 1) * 16 + lm) * 64 + (s & 1) * 32 + quad * 8;
    gv[i] = Vh + ((size_t)((s >> 2) * 16 + lm) * 8) * 128 + quad * 32 + (s & 3) * 8;
  }

  // prologue: stage blk_lo into buffer 0
#pragma unroll
  for (int i = 0; i < 4; ++i) {
    int s = w * 4 + i;
    GLD_LDS16(gk[i] + (size_t)blk_lo * 8192, &KLs[0][s * 512]);
    GLD_LDS16(gv[i] + (size_t)blk_lo * 128,  &VLs[0][s * 512]);
  }

  int cur = 0;
  for (int kb = blk_lo; kb < 8; ++kb) {
    __syncthreads();   // drains vmcnt -> staged buffer [cur] is ready
    if (kb + 1 < 8) {
      int nxt = cur ^ 1;
#pragma unroll
      for (int i = 0; i < 4; ++i) {
        int s = w * 4 + i;
        GLD_LDS16(gk[i] + (size_t)(kb + 1) * 8192, &KLs[nxt][s * 512]);
        GLD_LDS16(gv[i] + (size_t)(kb + 1) * 128,  &VLs[nxt][s * 512]);
      }
    }
    if (kb >= my_lo) {
      const unsigned short* Kc = &KLs[cur][0];
      const _Float16* Vc = &VLs[cur][0];
      const int k0 = kb * 128;
      const bool need_mask = (kb <= qb);

      // prefetch j=0 fragments
      short8 kA = *(const short8*)&Kc[(0 * 64 + lane) * 8];
      short8 kB = *(const short8*)&Kc[(1 * 64 + lane) * 8];
      half4 vA0 = *(const half4*)&Vc[((0 * 4 + 0) * 64 + lane) * 8];
      half4 vA1 = *(const half4*)&Vc[((1 * 4 + 0) * 64 + lane) * 8];
      half4 vA2 = *(const half4*)&Vc[((2 * 4 + 0) * 64 + lane) * 8];
      half4 vA3 = *(const half4*)&Vc[((3 * 4 + 0) * 64 + lane) * 8];

#pragma unroll
      for (int j = 0; j < 8; ++j) {
        short8 nA, nB; half4 n0, n1, n2, n3;
        if (j < 7) {
          int jn = j + 1;
          nA = *(const short8*)&Kc[((jn * 2 + 0) * 64 + lane) * 8];
          nB = *(const short8*)&Kc[((jn * 2 + 1) * 64 + lane) * 8];
          n0 = *(const half4*)&Vc[((0 * 4 + (jn >> 1)) * 64 + lane) * 8 + (jn & 1) * 4];
          n1 = *(const half4*)&Vc[((1 * 4 + (jn >> 1)) * 64 + lane) * 8 + (jn & 1) * 4];
          n2 = *(const half4*)&Vc[((2 * 4 + (jn >> 1)) * 64 + lane) * 8 + (jn & 1) * 4];
          n3 = *(const half4*)&Vc[((3 * 4 + (jn >> 1)) * 64 + lane) * 8 + (jn & 1) * 4];
        }
        // S-MFMAs
        floatx4 st[2];
#pragma unroll
        for (int qg = 0; qg < 2; ++qg) {
          floatx4 z = (floatx4){0.f, 0.f, 0.f, 0.f};
          z = __builtin_amdgcn_mfma_f32_16x16x32_bf16(kA, qf[qg][0], z, 0, 0, 0);
          st[qg] = __builtin_amdgcn_mfma_f32_16x16x32_bf16(kB, qf[qg][1], z, 0, 0, 0);
        }
        // softmax j
        half4 pa[2];
#pragma unroll
        for (int qg = 0; qg < 2; ++qg) {
          const int qq = qglob0 + qg * 16;
          const bool skip = (qg == 1) && excl1;
#pragma unroll
          for (int r = 0; r < 4; ++r) {
            int kg = k0 + j * 16 + quad * 4 + r;
            float v = st[qg][r];
            if (need_mask && !skip && kg <= qq) v -= MSHIFT;
            float p = __builtin_amdgcn_exp2f(v);
            lsum[qg] += p;
            pa[qg][r] = (_Float16)p;
          }
        }
        // PV j
        acc[0][0] = __builtin_amdgcn_mfma_f32_16x16x16f16(pa[0], vA0, acc[0][0], 0, 0, 0);
        acc[1][0] = __builtin_amdgcn_mfma_f32_16x16x16f16(pa[1], vA0, acc[1][0], 0, 0, 0);
        acc[0][1] = __builtin_amdgcn_mfma_f32_16x16x16f16(pa[0], vA1, acc[0][1], 0, 0, 0);
        acc[1][1] = __builtin_amdgcn_mfma_f32_16x16x16f16(pa[1], vA1, acc[1][1], 0, 0, 0);
        acc[0][2] = __builtin_amdgcn_mfma_f32_16x16x16f16(pa[0], vA2, acc[0][2], 0, 0, 0);
        acc[1][2] = __builtin_amdgcn_mfma_f32_16x16x16f16(pa[1], vA2, acc[1][2], 0, 0, 0);
        acc[0][3] = __builtin_amdgcn_mfma_f32_16x16x16f16(pa[0], vA3, acc[0][3], 0, 0, 0);
        acc[1][3] = __builtin_amdgcn_mfma_f32_16x16x16f16(pa[1], vA3, acc[1][3], 0, 0, 0);
        // rotate prefetched fragments
        kA = nA; kB = nB; vA0 = n0; vA1 = n1; vA2 = n2; vA3 = n3;
      }
    }
    cur ^= 1;
  }

  // epilogue
#pragma unroll
  for (int qg = 0; qg < 2; ++qg) {
    float l = lsum[qg];
    l += __shfl_xor(l, 16);
    l += __shfl_xor(l, 32);
    float s = maskp[bb * T_ + qglob0 + qg * 16] / l;
#pragma unroll
    for (int r = 0; r < 4; ++r) {
      float bsc = __shfl(s, quad * 4 + r);
      int tq = q0 + w * 32 + qg * 16 + quad * 4 + r;
#pragma unroll
      for (int j2 = 0; j2 < 4; ++j2)
        attn[((size_t)(bb * T_ + tq)) * D_ + hh * 64 + j2 * 16 + lm] = f2bf(acc[qg][j2][r] * bsc);
    }
  }
}

// ------------------- LN(x + attn_bf16) -> h1 f32+bf16 (wave-per-row)
__global__ __launch_bounds__(256)
void ln_res_kernel(const float* __restrict__ xa, const unsigned short* __restrict__ attn,
                   const float* __restrict__ sc, const float* __restrict__ bi,
                   float* __restrict__ h, unsigned short* __restrict__ hb) {
  const int t = threadIdx.x;
  const int lane = t & 63, w = t >> 6;
  const int row = blockIdx.x * 4 + w;
  const size_t base = (size_t)row * D_ + lane * 16;

  float v[16];
  float s1 = 0.f, s2 = 0.f;
#pragma unroll
  for (int i = 0; i < 4; ++i) {
    float4 a = *(const float4*)&xa[base + i * 4];
    union { uint2 u; unsigned short s[4]; } au;
    au.u = *(const uint2*)&attn[base + i * 4];
    float x0 = a.x + bf2f(au.s[0]);
    float x1 = a.y + bf2f(au.s[1]);
    float x2 = a.z + bf2f(au.s[2]);
    float x3 = a.w + bf2f(au.s[3]);
    v[i * 4 + 0] = x0; v[i * 4 + 1] = x1; v[i * 4 + 2] = x2; v[i * 4 + 3] = x3;
    s1 += x0 + x1 + x2 + x3;
    s2 += x0 * x0 + x1 * x1 + x2 * x2 + x3 * x3;
  }
#pragma unroll
  for (int off = 1; off < 64; off <<= 1) {
    s1 += __shfl_xor(s1, off);
    s2 += __shfl_xor(s2, off);
  }
  float mean = s1 * (1.f / 1024.f);
  float var = s2 * (1.f / 1024.f) - mean * mean;
  float rstd = rsqrtf(var + 1e-5f);
#pragma unroll
  for (int i = 0; i < 4; ++i) {
    float4 sv = *(const float4*)&sc[lane * 16 + i * 4];
    float4 bv = *(const float4*)&bi[lane * 16 + i * 4];
    float o0 = (v[i * 4 + 0] - mean) * rstd * sv.x + bv.x;
    float o1 = (v[i * 4 + 1] - mean) * rstd * sv.y + bv.y;
    float o2 = (v[i * 4 + 2] - mean) * rstd * sv.z + bv.z;
    float o3 = (v[i * 4 + 3] - mean) * rstd * sv.w + bv.w;
    float4 ov = {o0, o1, o2, o3};
    *(float4*)&h[base + i * 4] = ov;
    union { uint2 u; unsigned short s[4]; } ob;
    ob.s[0] = f2bf(o0); ob.s[1] = f2bf(o1); ob.s[2] = f2bf(o2); ob.s[3] = f2bf(o3);
    *(uint2*)&hb[base + i * 4] = ob.u;
  }
}

// ---------------- out = LN(LN(h1+ffn_bf16,ln2),ln3) (wave-per-row)
__global__ __launch_bounds__(256)
void ln_double_kernel(const float* __restrict__ h1, const unsigned short* __restrict__ ffnb,
                      const float* __restrict__ s2c, const float* __restrict__ b2c,
                      const float* __restrict__ s3c, const float* __restrict__ b3c,
                      float* __restrict__ out) {
  const int t = threadIdx.x;
  const int lane = t & 63, w = t >> 6;
  const int row = blockIdx.x * 4 + w;
  const size_t base = (size_t)row * D_ + lane * 16;

  float v[16];
  float s1 = 0.f, s2 = 0.f;
#pragma unroll
  for (int i = 0; i < 4; ++i) {
    float4 a = *(const float4*)&h1[base + i * 4];
    union { uint2 u; unsigned short s[4]; } fu;
    fu.u = *(const uint2*)&ffnb[base + i * 4];
    float x0 = a.x + bf2f(fu.s[0]);
    float x1 = a.y + bf2f(fu.s[1]);
    float x2 = a.z + bf2f(fu.s[2]);
    float x3 = a.w + bf2f(fu.s[3]);
    v[i * 4 + 0] = x0; v[i * 4 + 1] = x1; v[i * 4 + 2] = x2; v[i * 4 + 3] = x3;
    s1 += x0 + x1 + x2 + x3;
    s2 += x0 * x0 + x1 * x1 + x2 * x2 + x3 * x3;
  }
#pragma unroll
  for (int off = 1; off < 64; off <<= 1) {
    s1 += __shfl_xor(s1, off);
    s2 += __shfl_xor(s2, off);
  }
  float mean = s1 * (1.f / 1024.f);
  float var = s2 * (1.f / 1024.f) - mean * mean;
  float rstd = rsqrtf(var + 1e-5f);

  float o[16];
  float u1 = 0.f, u2 = 0.f;
#pragma unroll
  for (int i = 0; i < 4; ++i) {
    float4 sv = *(const float4*)&s2c[lane * 16 + i * 4];
    float4 bv = *(const float4*)&b2c[lane * 16 + i * 4];
    float o0 = (v[i * 4 + 0] - mean) * rstd * sv.x + bv.x;
    float o1 = (v[i * 4 + 1] - mean) * rstd * sv.y + bv.y;
    float o2 = (v[i * 4 + 2] - mean) * rstd * sv.z + bv.z;
    float o3 = (v[i * 4 + 3] - mean) * rstd * sv.w + bv.w;
    o[i * 4 + 0] = o0; o[i * 4 + 1] = o1; o[i * 4 + 2] = o2; o[i * 4 + 3] = o3;
    u1 += o0 + o1 + o2 + o3;
    u2 += o0 * o0 + o1 * o1 + o2 * o2 + o3 * o3;
  }
#pragma unroll
  for (int off = 1; off < 64; off <<= 1) {
    u1 += __shfl_xor(u1, off);
    u2 += __shfl_xor(u2, off);
  }
  float mean2 = u1 * (1.f / 1024.f);
  float var2 = u2 * (1.f / 1024.f) - mean2 * mean2;
  float rstd2 = rsqrtf(var2 + 1e-5f);
#pragma unroll
  for (int i = 0; i < 4; ++i) {
    float4 sv = *(const float4*)&s3c[lane * 16 + i * 4];
    float4 bv = *(const float4*)&b3c[lane * 16 + i * 4];
    float4 fo;
    fo.x = (o[i * 4 + 0] - mean2) * rstd2 * sv.x + bv.x;
    fo.y = (o[i * 4 + 1] - mean2) * rstd2 * sv.y + bv.y;
    fo.z = (o[i * 4 + 2] - mean2) * rstd2 * sv.z + bv.z;
    fo.w = (o[i * 4 + 3] - mean2) * rstd2 * sv.w + bv.w;
    *(float4*)&out[base + i * 4] = fo;
  }
}

// ------------------------------------------------------------------ launch
extern "C" void kernel_launch(void* const* d_in, const int* in_sizes, int n_in,
                              void* d_out, int out_size, void* d_ws, size_t ws_size,
                              hipStream_t stream) {
  (void)in_sizes; (void)n_in; (void)out_size; (void)ws_size;
  const float* x   = (const float*)d_in[0];
  const float* msk = (const float*)d_in[1];
  const float* wq  = (const float*)d_in[2];
  const float* wk  = (const float*)d_in[3];
  const float* wv  = (const float*)d_in[4];
  const float* w1  = (const float*)d_in[5];
  const float* b1  = (const float*)d_in[6];
  const float* w2  = (const float*)d_in[7];
  const float* b2  = (const float*)d_in[8];
  const float* l1s = (const float*)d_in[9];
  const float* l1b = (const float*)d_in[10];
  const float* l2s = (const float*)d_in[11];
  const float* l2b = (const float*)d_in[12];
  const float* l3s = (const float*)d_in[13];
  const float* l3b = (const float*)d_in[14];
  float* outp = (float*)d_out;

  char* ws = (char*)d_ws;
  unsigned short* xb   = (unsigned short*)(ws);                       // 8 MB
  unsigned short* wt   = (unsigned short*)(ws + ((size_t)8  << 20));  // 10 MB
  unsigned short* Qb   = (unsigned short*)(ws + ((size_t)18 << 20));  // 8 MB [B,H,T,DH]
  unsigned short* Kb   = (unsigned short*)(ws + ((size_t)26 << 20));  // 8 MB
  _Float16*       Vtg  = (_Float16*)(ws + ((size_t)34 << 20));        // 8 MB k-shuffled V^T
  unsigned short* attn = (unsigned short*)(ws + ((size_t)42 << 20));  // 8 MB bf16 [B,T,D]
  float* h1            = (float*)(ws + ((size_t)50 << 20));           // 16 MB
  unsigned short* h1b  = (unsigned short*)(ws + ((size_t)18 << 20));  // reuse Qb
  unsigned short* gb   = (unsigned short*)(ws + ((size_t)26 << 20));  // reuse Kb
  unsigned short* ffnb = (unsigned short*)(ws + ((size_t)34 << 20));  // reuse Vtg (8 MB bf16)

  prep_kernel<<<1024 + 1280, 256, 0, stream>>>((const float4*)x, xb,
                                               wq, wk, wv, w1, w2, wt);
  gemm_qkv<<<dim3(24, 32), 256, 0, stream>>>(xb, wt, Qb, Kb, Vtg);
  flash_attn<<<512, 256, 0, stream>>>(Qb, Kb, Vtg, msk, attn);
  ln_res_kernel<<<1024, 256, 0, stream>>>(x, attn, l1s, l1b, h1, h1b);
  gemm_ffn<1><<<dim3(8, 64), 256, 0, stream>>>(h1b, wt + (size_t)3 * 1024 * 1024, gb, b1);
  gemm_ffn<2><<<dim3(8, 64), 256, 0, stream>>>(gb, wt + (size_t)4 * 1024 * 1024, ffnb, b2);
  ln_double_kernel<<<1024, 256, 0, stream>>>(h1, ffnb, l2s, l2b, l3s, l3b, outp);
}

// Round 10
// 224.233 us; speedup vs baseline: 1.0547x; 1.0169x over previous
//
#include <hip/hip_runtime.h>
#include <stdint.h>

// B=4, T=1024, D=1024, H=16, DH=64. fp32 in/out, absmax thr 0.1.
// R18 vs R17: eliminate the fp32 h1 round-trip. ln_res wrote h1 f32 (16MB)
// + h1b bf16; ln_double read the f32 copy. bf16 rounding of h1 (~0.4% rel)
// costs ~0.005 absmax (headroom 0.031->0.1). ln_res now writes ONLY bf16
// (24->8MB), ln_double reads bf16 (24->16MB): -32MB traffic ~ -5us.
// GEMMs/flash byte-identical to R17 (228.0us proven):
//  - qkv: BK=64, Cs overlaid on As+Bs (34.8KB -> 3 blocks/CU).
//  - ffn: BK=64, XOR-swizzled staging/reads.
//  - flash: K+V LDS double-buffered, R12 XCD decode.

#define B_  4
#define T_  1024
#define D_  1024
#define H_  16
#define DH_ 64

typedef __attribute__((ext_vector_type(8))) short short8;
typedef __attribute__((ext_vector_type(4))) float floatx4;
typedef __attribute__((ext_vector_type(4))) _Float16 half4;

__device__ __forceinline__ unsigned short f2bf(float f) {
  union { float f; uint32_t u; } a; a.f = f;
  uint32_t r = a.u + 0x7FFFu + ((a.u >> 16) & 1u);
  return (unsigned short)(r >> 16);
}
__device__ __forceinline__ float bf2f(unsigned short u) {
  union { uint32_t u; float f; } a; a.u = ((uint32_t)u) << 16;
  return a.f;
}

#define GLD_LDS16(g, l) __builtin_amdgcn_global_load_lds( \
    (const __attribute__((address_space(1))) unsigned int*)(g), \
    (__attribute__((address_space(3))) unsigned int*)(l), 16, 0, 0)

// ---------------------------------------------- prep: cast x + transpose W
__global__ __launch_bounds__(256)
void prep_kernel(const float4* __restrict__ x4, unsigned short* __restrict__ xb,
                 const float* __restrict__ w0, const float* __restrict__ w1,
                 const float* __restrict__ w2, const float* __restrict__ w3,
                 const float* __restrict__ w4, unsigned short* __restrict__ dst_all) {
  const int t = threadIdx.x;
  if (blockIdx.x < 1024) {
    int idx0 = blockIdx.x * 1024 + t;
#pragma unroll
    for (int c = 0; c < 4; ++c) {
      int idx = idx0 + c * 256;
      float4 v = x4[idx];
      union { uint2 u; unsigned short s[4]; } o;
      o.s[0] = f2bf(v.x); o.s[1] = f2bf(v.y); o.s[2] = f2bf(v.z); o.s[3] = f2bf(v.w);
      *(uint2*)&xb[(size_t)idx * 4] = o.u;
    }
    return;
  }
  const int b = blockIdx.x - 1024;
  const int z = b >> 8, ky = (b >> 4) & 15, nx = b & 15;
  const float* src = (z == 0) ? w0 : (z == 1) ? w1 : (z == 2) ? w2 : (z == 3) ? w3 : w4;
  unsigned short* dst = dst_all + (size_t)z * D_ * D_;
  __shared__ __align__(16) unsigned short tile[64 * 72];
  const int k0 = ky * 64, n0 = nx * 64;
#pragma unroll
  for (int c = 0; c < 4; ++c) {
    int idx = c * 256 + t;
    int r = idx >> 4, cc = (idx & 15) << 2;
    float4 v = *(const float4*)&src[(size_t)(k0 + r) * D_ + n0 + cc];
    tile[(cc + 0) * 72 + r] = f2bf(v.x);
    tile[(cc + 1) * 72 + r] = f2bf(v.y);
    tile[(cc + 2) * 72 + r] = f2bf(v.z);
    tile[(cc + 3) * 72 + r] = f2bf(v.w);
  }
  __syncthreads();
  int rr = t >> 2, ck = (t & 3) << 4;
  uint4 v0 = *(const uint4*)&tile[rr * 72 + ck];
  uint4 v1 = *(const uint4*)&tile[rr * 72 + ck + 8];
  *(uint4*)&dst[(size_t)(n0 + rr) * D_ + k0 + ck] = v0;
  *(uint4*)&dst[(size_t)(n0 + rr) * D_ + k0 + ck + 8] = v1;
}

// ------------------------------------------------------------------ QKV GEMM
// BK=64, Cs overlaid on As+Bs (LDS 34816B -> 3 blocks/CU at grid 768).
__global__ __launch_bounds__(256, 2)
void gemm_qkv(const unsigned short* __restrict__ A,
              const unsigned short* __restrict__ Bt,
              unsigned short* __restrict__ oQ, unsigned short* __restrict__ oK,
              _Float16* __restrict__ oV) {
  const int K = 1024;
  __shared__ __align__(16) unsigned char smem[34816];   // max(As+Bs=32KB, Cs=34KB)
  unsigned short* As = (unsigned short*)smem;           // 128x64 = 16KB
  unsigned short* Bs = (unsigned short*)(smem + 16384); // 128x64 = 16KB
  _Float16* Cs = (_Float16*)smem;                       // 2*64*136 (post-loop)
  const int t = threadIdx.x;
  const int lane = t & 63, w = t >> 6;
  const int quad = lane >> 4, lm = lane & 15;
  const int wm = w >> 1, wn = w & 1;
  const int m0 = blockIdx.y * 128, n0 = blockIdx.x * 128;
  // staging: lane l covers row i*8+(l>>3) of its wave's 32-row strip,
  // LDS slot (l&7); global chunk = (l&7)^((l>>3)&7)  [row key = row&7]
  const int srow = lane >> 3;
  const int scol = ((lane & 7) ^ srow) << 3;

  floatx4 acc[4][4];
#pragma unroll
  for (int i = 0; i < 4; ++i)
#pragma unroll
    for (int j = 0; j < 4; ++j) acc[i][j] = (floatx4){0.f, 0.f, 0.f, 0.f};

  for (int kt = 0; kt < K; kt += 64) {
#pragma unroll
    for (int i = 0; i < 4; ++i) {
      const unsigned short* ga = A + (size_t)(m0 + w * 32 + i * 8 + srow) * K + kt + scol;
      const unsigned short* gb = Bt + (size_t)(n0 + w * 32 + i * 8 + srow) * K + kt + scol;
      GLD_LDS16(ga, &As[w * 2048 + i * 512]);
      GLD_LDS16(gb, &Bs[w * 2048 + i * 512]);
    }
    __syncthreads();
#pragma unroll
    for (int ks = 0; ks < 2; ++ks) {
      const int rs = ((ks * 4 + quad) ^ (lm & 7)) << 3;   // read slot (free: 2/bank)
      short8 a[4], b[4];
#pragma unroll
      for (int i = 0; i < 4; ++i) a[i] = *(const short8*)&As[(wm * 64 + i * 16 + lm) * 64 + rs];
#pragma unroll
      for (int j = 0; j < 4; ++j) b[j] = *(const short8*)&Bs[(wn * 64 + j * 16 + lm) * 64 + rs];
#pragma unroll
      for (int i = 0; i < 4; ++i)
#pragma unroll
        for (int j = 0; j < 4; ++j)
          acc[i][j] = __builtin_amdgcn_mfma_f32_16x16x32_bf16(a[i], b[j], acc[i][j], 0, 0, 0);
    }
    __syncthreads();
  }

  if (n0 < 2048) {
    unsigned short* p = (n0 < 1024) ? oQ : oK;
    const float qscale = (n0 < 1024) ? 0.18033688f : 1.0f;   // 0.125*log2(e)
#pragma unroll
    for (int i = 0; i < 4; ++i) {
      int gmb = m0 + wm * 64 + i * 16 + quad * 4;
#pragma unroll
      for (int j = 0; j < 4; ++j) {
        int gn = n0 + wn * 64 + j * 16 + lm;
        int nn = gn & 1023, hh = nn >> 6, dd = nn & 63;
#pragma unroll
        for (int r = 0; r < 4; ++r) {
          int gm = gmb + r;
          int bb = gm >> 10, tt = gm & 1023;
          p[(((size_t)bb * H_ + hh) * T_ + tt) * DH_ + dd] = f2bf(acc[i][j][r] * qscale);
        }
      }
    }
  } else {
#pragma unroll
    for (int i = 0; i < 4; ++i) {
#pragma unroll
      for (int j = 0; j < 4; ++j) {
        int gn = n0 + wn * 64 + j * 16 + lm;
        int hd = (gn >> 6) & 1, dd = gn & 63;
        int kperm = quad * 32 + (wm * 4 + i) * 4;
        union { _Float16 h[4]; uint2 u; } pk;
#pragma unroll
        for (int r = 0; r < 4; ++r) pk.h[r] = (_Float16)acc[i][j][r];
        *(uint2*)&Cs[((size_t)(hd * 64 + dd)) * 136 + kperm] = pk.u;
      }
    }
    __syncthreads();
    const int row = t >> 1, half = t & 1;
    const int hd = row >> 6, dd = row & 63;
    const int hh = ((n0 & 1023) >> 6) + hd;
    const int bb = m0 >> 10, kbg = (m0 >> 7) & 7;
    const _Float16* srcp = &Cs[(size_t)(hd * 64 + dd) * 136 + half * 64];
    _Float16* dstp = oV + ((((size_t)bb * H_ + hh) * DH_ + dd) * 8 + kbg) * 128 + half * 64;
#pragma unroll
    for (int g = 0; g < 8; ++g)
      *(uint4*)(dstp + g * 8) = *(const uint4*)(srcp + g * 8);
  }
}

// ------------------------------------------------------------ FFN GEMM 64x128
// BK=64 (barriers 16). MODE 1: relu->bf16. MODE 2: plain->bf16.
template <int MODE>
__global__ __launch_bounds__(256, 2)
void gemm_ffn(const unsigned short* __restrict__ A,
              const unsigned short* __restrict__ Bt,
              unsigned short* __restrict__ oBf,
              const float* __restrict__ bias) {
  const int K = 1024, N = 1024;
  __shared__ __align__(16) unsigned short As[64 * 64];    // 8KB
  __shared__ __align__(16) unsigned short Bs[128 * 64];   // 16KB
  const int t = threadIdx.x;
  const int lane = t & 63, w = t >> 6;
  const int quad = lane >> 4, lm = lane & 15;
  const int wm = w >> 1, wn = w & 1;
  const int m0 = blockIdx.y * 64, n0 = blockIdx.x * 128;
  const int srow = lane >> 3;
  const int scol = ((lane & 7) ^ srow) << 3;

  floatx4 acc[2][4];
#pragma unroll
  for (int i = 0; i < 2; ++i)
#pragma unroll
    for (int j = 0; j < 4; ++j) acc[i][j] = (floatx4){0.f, 0.f, 0.f, 0.f};

  for (int kt = 0; kt < K; kt += 64) {
#pragma unroll
    for (int i = 0; i < 2; ++i) {
      const unsigned short* ga = A + (size_t)(m0 + w * 16 + i * 8 + srow) * K + kt + scol;
      GLD_LDS16(ga, &As[w * 1024 + i * 512]);
    }
#pragma unroll
    for (int i = 0; i < 4; ++i) {
      const unsigned short* gb = Bt + (size_t)(n0 + w * 32 + i * 8 + srow) * K + kt + scol;
      GLD_LDS16(gb, &Bs[w * 2048 + i * 512]);
    }
    __syncthreads();
#pragma unroll
    for (int ks = 0; ks < 2; ++ks) {
      const int rs = ((ks * 4 + quad) ^ (lm & 7)) << 3;
      short8 a[2], b[4];
#pragma unroll
      for (int i = 0; i < 2; ++i) a[i] = *(const short8*)&As[(wm * 32 + i * 16 + lm) * 64 + rs];
#pragma unroll
      for (int j = 0; j < 4; ++j) b[j] = *(const short8*)&Bs[(wn * 64 + j * 16 + lm) * 64 + rs];
#pragma unroll
      for (int i = 0; i < 2; ++i)
#pragma unroll
        for (int j = 0; j < 4; ++j)
          acc[i][j] = __builtin_amdgcn_mfma_f32_16x16x32_bf16(a[i], b[j], acc[i][j], 0, 0, 0);
    }
    __syncthreads();
  }

#pragma unroll
  for (int i = 0; i < 2; ++i) {
    int gmb = m0 + wm * 32 + i * 16 + quad * 4;
#pragma unroll
    for (int j = 0; j < 4; ++j) {
      int gn = n0 + wn * 64 + j * 16 + lm;
      float bv = bias[gn];
#pragma unroll
      for (int r = 0; r < 4; ++r) {
        int gm = gmb + r;
        float v = acc[i][j][r] + bv;
        if (MODE == 1) v = fmaxf(v, 0.f);
        oBf[(size_t)gm * N + gn] = f2bf(v);
      }
    }
  }
}

// --------------------------------------------------------------- flash attn
// 512 blocks x 256 thr; R12 decode; K+V LDS double-buffered (R14).
__global__ __launch_bounds__(256)
void flash_attn(const unsigned short* __restrict__ Qb,
                const unsigned short* __restrict__ Kb,
                const _Float16* __restrict__ Vtg,
                const float* __restrict__ maskp,
                unsigned short* __restrict__ attn) {
  __shared__ __align__(16) unsigned short KLs[2][8192];  // 2 x 16 KB
  __shared__ __align__(16) _Float16      VLs[2][8192];   // 2 x 16 KB

  const int t = threadIdx.x;
  const int lane = t & 63, w = t >> 6;
  const int quad = lane >> 4, lm = lane & 15;

  const int bid = blockIdx.x;               // 0..511
  const int hi  = bid >> 8;                 // 0/1: co-residency half
  const int lo  = bid & 255;
  const int xcd = lo & 7;
  const int hgrp = (lo >> 3) & 7;
  const int qpair = lo >> 6;                // 0..3
  const int qb = hi ? (7 - qpair) : qpair;  // pair (p, 7-p) share a CU
  const int head = hgrp * 8 + xcd;          // 0..63; head%8 = XCD
  const int hh = head & 15, bb = head >> 4;
  const int q0 = qb << 7;

  const size_t headoff = ((size_t)bb * H_ + hh) * T_ * DH_;
  const unsigned short* Qh = Qb + headoff;
  const unsigned short* Kh = Kb + headoff;
  const _Float16* Vh = Vtg + headoff;   // k-shuffled [d][kb][quad][j][r]

  short8 qf[2][2];
#pragma unroll
  for (int qg = 0; qg < 2; ++qg)
#pragma unroll
    for (int ks = 0; ks < 2; ++ks)
      qf[qg][ks] = *(const short8*)(Qh + (size_t)(q0 + w * 32 + qg * 16 + lm) * 64 + ks * 32 + quad * 8);

  float lsum[2] = {0.f, 0.f};
  floatx4 acc[2][4];
#pragma unroll
  for (int qg = 0; qg < 2; ++qg)
#pragma unroll
    for (int j2 = 0; j2 < 4; ++j2) acc[qg][j2] = (floatx4){0.f, 0.f, 0.f, 0.f};

  const int qglob0 = q0 + w * 32 + lm;
  const bool excl1 = (qglob0 + 16 == 1023);   // row-1023 lane (qg=1 only)
  const float MSHIFT = 14426.950408f;          // 10000*log2(e)

  const int my_lo  = (qb == 7 && w == 3) ? 0 : qb;  // this wave's first kb
  const int blk_lo = (qb == 7) ? 0 : qb;            // block staging range

  // per-wave staging source addresses (slots s = w*4 .. w*4+3)
  const unsigned short* gk[4];
  const _Float16* gv[4];
#pragma unroll
  for (int i = 0; i < 4; ++i) {
    int s = w * 4 + i;
    gk[i] = Kh + (size_t)((s >> 1) * 16 + lm) * 64 + (s & 1) * 32 + quad * 8;
    gv[i] = Vh + ((size_t)((s >> 2) * 16 + lm) * 8) * 128 + quad * 32 + (s & 3) * 8;
  }

  // prologue: stage blk_lo into buffer 0
#pragma unroll
  for (int i = 0; i < 4; ++i) {
    int s = w * 4 + i;
    GLD_LDS16(gk[i] + (size_t)blk_lo * 8192, &KLs[0][s * 512]);
    GLD_LDS16(gv[i] + (size_t)blk_lo * 128,  &VLs[0][s * 512]);
  }

  int cur = 0;
  for (int kb = blk_lo; kb < 8; ++kb) {
    __syncthreads();   // drains vmcnt -> staged buffer [cur] is ready
    if (kb + 1 < 8) {
      int nxt = cur ^ 1;
#pragma unroll
      for (int i = 0; i < 4; ++i) {
        int s = w * 4 + i;
        GLD_LDS16(gk[i] + (size_t)(kb + 1) * 8192, &KLs[nxt][s * 512]);
        GLD_LDS16(gv[i] + (size_t)(kb + 1) * 128,  &VLs[nxt][s * 512]);
      }
    }
    if (kb >= my_lo) {
      const unsigned short* Kc = &KLs[cur][0];
      const _Float16* Vc = &VLs[cur][0];
      const int k0 = kb * 128;
      const bool need_mask = (kb <= qb);

      // prefetch j=0 fragments
      short8 kA = *(const short8*)&Kc[(0 * 64 + lane) * 8];
      short8 kB = *(const short8*)&Kc[(1 * 64 + lane) * 8];
      half4 vA0 = *(const half4*)&Vc[((0 * 4 + 0) * 64 + lane) * 8];
      half4 vA1 = *(const half4*)&Vc[((1 * 4 + 0) * 64 + lane) * 8];
      half4 vA2 = *(const half4*)&Vc[((2 * 4 + 0) * 64 + lane) * 8];
      half4 vA3 = *(const half4*)&Vc[((3 * 4 + 0) * 64 + lane) * 8];

#pragma unroll
      for (int j = 0; j < 8; ++j) {
        short8 nA, nB; half4 n0, n1, n2, n3;
        if (j < 7) {
          int jn = j + 1;
          nA = *(const short8*)&Kc[((jn * 2 + 0) * 64 + lane) * 8];
          nB = *(const short8*)&Kc[((jn * 2 + 1) * 64 + lane) * 8];
          n0 = *(const half4*)&Vc[((0 * 4 + (jn >> 1)) * 64 + lane) * 8 + (jn & 1) * 4];
          n1 = *(const half4*)&Vc[((1 * 4 + (jn >> 1)) * 64 + lane) * 8 + (jn & 1) * 4];
          n2 = *(const half4*)&Vc[((2 * 4 + (jn >> 1)) * 64 + lane) * 8 + (jn & 1) * 4];
          n3 = *(const half4*)&Vc[((3 * 4 + (jn >> 1)) * 64 + lane) * 8 + (jn & 1) * 4];
        }
        // S-MFMAs
        floatx4 st[2];
#pragma unroll
        for (int qg = 0; qg < 2; ++qg) {
          floatx4 z = (floatx4){0.f, 0.f, 0.f, 0.f};
          z = __builtin_amdgcn_mfma_f32_16x16x32_bf16(kA, qf[qg][0], z, 0, 0, 0);
          st[qg] = __builtin_amdgcn_mfma_f32_16x16x32_bf16(kB, qf[qg][1], z, 0, 0, 0);
        }
        // softmax j
        half4 pa[2];
#pragma unroll
        for (int qg = 0; qg < 2; ++qg) {
          const int qq = qglob0 + qg * 16;
          const bool skip = (qg == 1) && excl1;
#pragma unroll
          for (int r = 0; r < 4; ++r) {
            int kg = k0 + j * 16 + quad * 4 + r;
            float v = st[qg][r];
            if (need_mask && !skip && kg <= qq) v -= MSHIFT;
            float p = __builtin_amdgcn_exp2f(v);
            lsum[qg] += p;
            pa[qg][r] = (_Float16)p;
          }
        }
        // PV j
        acc[0][0] = __builtin_amdgcn_mfma_f32_16x16x16f16(pa[0], vA0, acc[0][0], 0, 0, 0);
        acc[1][0] = __builtin_amdgcn_mfma_f32_16x16x16f16(pa[1], vA0, acc[1][0], 0, 0, 0);
        acc[0][1] = __builtin_amdgcn_mfma_f32_16x16x16f16(pa[0], vA1, acc[0][1], 0, 0, 0);
        acc[1][1] = __builtin_amdgcn_mfma_f32_16x16x16f16(pa[1], vA1, acc[1][1], 0, 0, 0);
        acc[0][2] = __builtin_amdgcn_mfma_f32_16x16x16f16(pa[0], vA2, acc[0][2], 0, 0, 0);
        acc[1][2] = __builtin_amdgcn_mfma_f32_16x16x16f16(pa[1], vA2, acc[1][2], 0, 0, 0);
        acc[0][3] = __builtin_amdgcn_mfma_f32_16x16x16f16(pa[0], vA3, acc[0][3], 0, 0, 0);
        acc[1][3] = __builtin_amdgcn_mfma_f32_16x16x16f16(pa[1], vA3, acc[1][3], 0, 0, 0);
        // rotate prefetched fragments
        kA = nA; kB = nB; vA0 = n0; vA1 = n1; vA2 = n2; vA3 = n3;
      }
    }
    cur ^= 1;
  }

  // epilogue
#pragma unroll
  for (int qg = 0; qg < 2; ++qg) {
    float l = lsum[qg];
    l += __shfl_xor(l, 16);
    l += __shfl_xor(l, 32);
    float s = maskp[bb * T_ + qglob0 + qg * 16] / l;
#pragma unroll
    for (int r = 0; r < 4; ++r) {
      float bsc = __shfl(s, quad * 4 + r);
      int tq = q0 + w * 32 + qg * 16 + quad * 4 + r;
#pragma unroll
      for (int j2 = 0; j2 < 4; ++j2)
        attn[((size_t)(bb * T_ + tq)) * D_ + hh * 64 + j2 * 16 + lm] = f2bf(acc[qg][j2][r] * bsc);
    }
  }
}

// ------------------- LN(x + attn_bf16) -> h1b bf16 only (wave-per-row)
__global__ __launch_bounds__(256)
void ln_res_kernel(const float* __restrict__ xa, const unsigned short* __restrict__ attn,
                   const float* __restrict__ sc, const float* __restrict__ bi,
                   unsigned short* __restrict__ hb) {
  const int t = threadIdx.x;
  const int lane = t & 63, w = t >> 6;
  const int row = blockIdx.x * 4 + w;
  const size_t base = (size_t)row * D_ + lane * 16;

  float v[16];
  float s1 = 0.f, s2 = 0.f;
#pragma unroll
  for (int i = 0; i < 4; ++i) {
    float4 a = *(const float4*)&xa[base + i * 4];
    union { uint2 u; unsigned short s[4]; } au;
    au.u = *(const uint2*)&attn[base + i * 4];
    float x0 = a.x + bf2f(au.s[0]);
    float x1 = a.y + bf2f(au.s[1]);
    float x2 = a.z + bf2f(au.s[2]);
    float x3 = a.w + bf2f(au.s[3]);
    v[i * 4 + 0] = x0; v[i * 4 + 1] = x1; v[i * 4 + 2] = x2; v[i * 4 + 3] = x3;
    s1 += x0 + x1 + x2 + x3;
    s2 += x0 * x0 + x1 * x1 + x2 * x2 + x3 * x3;
  }
#pragma unroll
  for (int off = 1; off < 64; off <<= 1) {
    s1 += __shfl_xor(s1, off);
    s2 += __shfl_xor(s2, off);
  }
  float mean = s1 * (1.f / 1024.f);
  float var = s2 * (1.f / 1024.f) - mean * mean;
  float rstd = rsqrtf(var + 1e-5f);
#pragma unroll
  for (int i = 0; i < 4; ++i) {
    float4 sv = *(const float4*)&sc[lane * 16 + i * 4];
    float4 bv = *(const float4*)&bi[lane * 16 + i * 4];
    float o0 = (v[i * 4 + 0] - mean) * rstd * sv.x + bv.x;
    float o1 = (v[i * 4 + 1] - mean) * rstd * sv.y + bv.y;
    float o2 = (v[i * 4 + 2] - mean) * rstd * sv.z + bv.z;
    float o3 = (v[i * 4 + 3] - mean) * rstd * sv.w + bv.w;
    union { uint2 u; unsigned short s[4]; } ob;
    ob.s[0] = f2bf(o0); ob.s[1] = f2bf(o1); ob.s[2] = f2bf(o2); ob.s[3] = f2bf(o3);
    *(uint2*)&hb[base + i * 4] = ob.u;
  }
}

// ---------------- out = LN(LN(h1b+ffnb,ln2),ln3) (wave-per-row, both bf16)
__global__ __launch_bounds__(256)
void ln_double_kernel(const unsigned short* __restrict__ h1b,
                      const unsigned short* __restrict__ ffnb,
                      const float* __restrict__ s2c, const float* __restrict__ b2c,
                      const float* __restrict__ s3c, const float* __restrict__ b3c,
                      float* __restrict__ out) {
  const int t = threadIdx.x;
  const int lane = t & 63, w = t >> 6;
  const int row = blockIdx.x * 4 + w;
  const size_t base = (size_t)row * D_ + lane * 16;

  float v[16];
  float s1 = 0.f, s2 = 0.f;
#pragma unroll
  for (int i = 0; i < 4; ++i) {
    union { uint2 u; unsigned short s[4]; } hu, fu;
    hu.u = *(const uint2*)&h1b[base + i * 4];
    fu.u = *(const uint2*)&ffnb[base + i * 4];
    float x0 = bf2f(hu.s[0]) + bf2f(fu.s[0]);
    float x1 = bf2f(hu.s[1]) + bf2f(fu.s[1]);
    float x2 = bf2f(hu.s[2]) + bf2f(fu.s[2]);
    float x3 = bf2f(hu.s[3]) + bf2f(fu.s[3]);
    v[i * 4 + 0] = x0; v[i * 4 + 1] = x1; v[i * 4 + 2] = x2; v[i * 4 + 3] = x3;
    s1 += x0 + x1 + x2 + x3;
    s2 += x0 * x0 + x1 * x1 + x2 * x2 + x3 * x3;
  }
#pragma unroll
  for (int off = 1; off < 64; off <<= 1) {
    s1 += __shfl_xor(s1, off);
    s2 += __shfl_xor(s2, off);
  }
  float mean = s1 * (1.f / 1024.f);
  float var = s2 * (1.f / 1024.f) - mean * mean;
  float rstd = rsqrtf(var + 1e-5f);

  float o[16];
  float u1 = 0.f, u2 = 0.f;
#pragma unroll
  for (int i = 0; i < 4; ++i) {
    float4 sv = *(const float4*)&s2c[lane * 16 + i * 4];
    float4 bv = *(const float4*)&b2c[lane * 16 + i * 4];
    float o0 = (v[i * 4 + 0] - mean) * rstd * sv.x + bv.x;
    float o1 = (v[i * 4 + 1] - mean) * rstd * sv.y + bv.y;
    float o2 = (v[i * 4 + 2] - mean) * rstd * sv.z + bv.z;
    float o3 = (v[i * 4 + 3] - mean) * rstd * sv.w + bv.w;
    o[i * 4 + 0] = o0; o[i * 4 + 1] = o1; o[i * 4 + 2] = o2; o[i * 4 + 3] = o3;
    u1 += o0 + o1 + o2 + o3;
    u2 += o0 * o0 + o1 * o1 + o2 * o2 + o3 * o3;
  }
#pragma unroll
  for (int off = 1; off < 64; off <<= 1) {
    u1 += __shfl_xor(u1, off);
    u2 += __shfl_xor(u2, off);
  }
  float mean2 = u1 * (1.f / 1024.f);
  float var2 = u2 * (1.f / 1024.f) - mean2 * mean2;
  float rstd2 = rsqrtf(var2 + 1e-5f);
#pragma unroll
  for (int i = 0; i < 4; ++i) {
    float4 sv = *(const float4*)&s3c[lane * 16 + i * 4];
    float4 bv = *(const float4*)&b3c[lane * 16 + i * 4];
    float4 fo;
    fo.x = (o[i * 4 + 0] - mean2) * rstd2 * sv.x + bv.x;
    fo.y = (o[i * 4 + 1] - mean2) * rstd2 * sv.y + bv.y;
    fo.z = (o[i * 4 + 2] - mean2) * rstd2 * sv.z + bv.z;
    fo.w = (o[i * 4 + 3] - mean2) * rstd2 * sv.w + bv.w;
    *(float4*)&out[base + i * 4] = fo;
  }
}

// ------------------------------------------------------------------ launch
extern "C" void kernel_launch(void* const* d_in, const int* in_sizes, int n_in,
                              void* d_out, int out_size, void* d_ws, size_t ws_size,
                              hipStream_t stream) {
  (void)in_sizes; (void)n_in; (void)out_size; (void)ws_size;
  const float* x   = (const float*)d_in[0];
  const float* msk = (const float*)d_in[1];
  const float* wq  = (const float*)d_in[2];
  const float* wk  = (const float*)d_in[3];
  const float* wv  = (const float*)d_in[4];
  const float* w1  = (const float*)d_in[5];
  const float* b1  = (const float*)d_in[6];
  const float* w2  = (const float*)d_in[7];
  const float* b2  = (const float*)d_in[8];
  const float* l1s = (const float*)d_in[9];
  const float* l1b = (const float*)d_in[10];
  const float* l2s = (const float*)d_in[11];
  const float* l2b = (const float*)d_in[12];
  const float* l3s = (const float*)d_in[13];
  const float* l3b = (const float*)d_in[14];
  float* outp = (float*)d_out;

  char* ws = (char*)d_ws;
  unsigned short* xb   = (unsigned short*)(ws);                       // 8 MB
  unsigned short* wt   = (unsigned short*)(ws + ((size_t)8  << 20));  // 10 MB
  unsigned short* Qb   = (unsigned short*)(ws + ((size_t)18 << 20));  // 8 MB [B,H,T,DH]
  unsigned short* Kb   = (unsigned short*)(ws + ((size_t)26 << 20));  // 8 MB
  _Float16*       Vtg  = (_Float16*)(ws + ((size_t)34 << 20));        // 8 MB k-shuffled V^T
  unsigned short* attn = (unsigned short*)(ws + ((size_t)42 << 20));  // 8 MB bf16 [B,T,D]
  unsigned short* h1b  = (unsigned short*)(ws + ((size_t)18 << 20));  // reuse Qb (8 MB bf16)
  unsigned short* gb   = (unsigned short*)(ws + ((size_t)26 << 20));  // reuse Kb
  unsigned short* ffnb = (unsigned short*)(ws + ((size_t)34 << 20));  // reuse Vtg (8 MB bf16)

  prep_kernel<<<1024 + 1280, 256, 0, stream>>>((const float4*)x, xb,
                                               wq, wk, wv, w1, w2, wt);
  gemm_qkv<<<dim3(24, 32), 256, 0, stream>>>(xb, wt, Qb, Kb, Vtg);
  flash_attn<<<512, 256, 0, stream>>>(Qb, Kb, Vtg, msk, attn);
  ln_res_kernel<<<1024, 256, 0, stream>>>(x, attn, l1s, l1b, h1b);
  gemm_ffn<1><<<dim3(8, 64), 256, 0, stream>>>(h1b, wt + (size_t)3 * 1024 * 1024, gb, b1);
  gemm_ffn<2><<<dim3(8, 64), 256, 0, stream>>>(gb, wt + (size_t)4 * 1024 * 1024, ffnb, b2);
  ln_double_kernel<<<1024, 256, 0, stream>>>(h1b, ffnb, l2s, l2b, l3s, l3b, outp);
}

// Round 11
// 222.077 us; speedup vs baseline: 1.0649x; 1.0097x over previous
//
#include <hip/hip_runtime.h>
#include <stdint.h>

// B=4, T=1024, D=1024, H=16, DH=64. fp32 in/out, absmax thr 0.1.
// R19 vs R18: ln_res reads xb (bf16 cast of x, already produced by prep)
// instead of x f32: -8MB read. x~N(0,1) -> bf16 error ~0.2% rel -> final
// perturbation ~0.005 (headroom 0.031->0.1). Everything else identical to
// R18 (224.2us proven):
//  - qkv: BK=64, Cs overlaid on As+Bs (34.8KB -> 3 blocks/CU).
//  - ffn: BK=64, XOR-swizzled staging/reads, bf16 out.
//  - flash: K+V LDS double-buffered, R12 XCD decode.
//  - LNs: wave-per-row, bf16 intermediates (no f32 h1 round-trip).
// Remaining structure: qkv ~760TF = 87% of the 2-barrier-structure ceiling
// (8-phase rewrite needs 256^2 tiles -> 192 blocks < 256 CUs, high risk);
// ~85us of measured time is harness poison-fills (untouchable).

#define B_  4
#define T_  1024
#define D_  1024
#define H_  16
#define DH_ 64

typedef __attribute__((ext_vector_type(8))) short short8;
typedef __attribute__((ext_vector_type(4))) float floatx4;
typedef __attribute__((ext_vector_type(4))) _Float16 half4;

__device__ __forceinline__ unsigned short f2bf(float f) {
  union { float f; uint32_t u; } a; a.f = f;
  uint32_t r = a.u + 0x7FFFu + ((a.u >> 16) & 1u);
  return (unsigned short)(r >> 16);
}
__device__ __forceinline__ float bf2f(unsigned short u) {
  union { uint32_t u; float f; } a; a.u = ((uint32_t)u) << 16;
  return a.f;
}

#define GLD_LDS16(g, l) __builtin_amdgcn_global_load_lds( \
    (const __attribute__((address_space(1))) unsigned int*)(g), \
    (__attribute__((address_space(3))) unsigned int*)(l), 16, 0, 0)

// ---------------------------------------------- prep: cast x + transpose W
__global__ __launch_bounds__(256)
void prep_kernel(const float4* __restrict__ x4, unsigned short* __restrict__ xb,
                 const float* __restrict__ w0, const float* __restrict__ w1,
                 const float* __restrict__ w2, const float* __restrict__ w3,
                 const float* __restrict__ w4, unsigned short* __restrict__ dst_all) {
  const int t = threadIdx.x;
  if (blockIdx.x < 1024) {
    int idx0 = blockIdx.x * 1024 + t;
#pragma unroll
    for (int c = 0; c < 4; ++c) {
      int idx = idx0 + c * 256;
      float4 v = x4[idx];
      union { uint2 u; unsigned short s[4]; } o;
      o.s[0] = f2bf(v.x); o.s[1] = f2bf(v.y); o.s[2] = f2bf(v.z); o.s[3] = f2bf(v.w);
      *(uint2*)&xb[(size_t)idx * 4] = o.u;
    }
    return;
  }
  const int b = blockIdx.x - 1024;
  const int z = b >> 8, ky = (b >> 4) & 15, nx = b & 15;
  const float* src = (z == 0) ? w0 : (z == 1) ? w1 : (z == 2) ? w2 : (z == 3) ? w3 : w4;
  unsigned short* dst = dst_all + (size_t)z * D_ * D_;
  __shared__ __align__(16) unsigned short tile[64 * 72];
  const int k0 = ky * 64, n0 = nx * 64;
#pragma unroll
  for (int c = 0; c < 4; ++c) {
    int idx = c * 256 + t;
    int r = idx >> 4, cc = (idx & 15) << 2;
    float4 v = *(const float4*)&src[(size_t)(k0 + r) * D_ + n0 + cc];
    tile[(cc + 0) * 72 + r] = f2bf(v.x);
    tile[(cc + 1) * 72 + r] = f2bf(v.y);
    tile[(cc + 2) * 72 + r] = f2bf(v.z);
    tile[(cc + 3) * 72 + r] = f2bf(v.w);
  }
  __syncthreads();
  int rr = t >> 2, ck = (t & 3) << 4;
  uint4 v0 = *(const uint4*)&tile[rr * 72 + ck];
  uint4 v1 = *(const uint4*)&tile[rr * 72 + ck + 8];
  *(uint4*)&dst[(size_t)(n0 + rr) * D_ + k0 + ck] = v0;
  *(uint4*)&dst[(size_t)(n0 + rr) * D_ + k0 + ck + 8] = v1;
}

// ------------------------------------------------------------------ QKV GEMM
// BK=64, Cs overlaid on As+Bs (LDS 34816B -> 3 blocks/CU at grid 768).
__global__ __launch_bounds__(256, 2)
void gemm_qkv(const unsigned short* __restrict__ A,
              const unsigned short* __restrict__ Bt,
              unsigned short* __restrict__ oQ, unsigned short* __restrict__ oK,
              _Float16* __restrict__ oV) {
  const int K = 1024;
  __shared__ __align__(16) unsigned char smem[34816];   // max(As+Bs=32KB, Cs=34KB)
  unsigned short* As = (unsigned short*)smem;           // 128x64 = 16KB
  unsigned short* Bs = (unsigned short*)(smem + 16384); // 128x64 = 16KB
  _Float16* Cs = (_Float16*)smem;                       // 2*64*136 (post-loop)
  const int t = threadIdx.x;
  const int lane = t & 63, w = t >> 6;
  const int quad = lane >> 4, lm = lane & 15;
  const int wm = w >> 1, wn = w & 1;
  const int m0 = blockIdx.y * 128, n0 = blockIdx.x * 128;
  // staging: lane l covers row i*8+(l>>3) of its wave's 32-row strip,
  // LDS slot (l&7); global chunk = (l&7)^((l>>3)&7)  [row key = row&7]
  const int srow = lane >> 3;
  const int scol = ((lane & 7) ^ srow) << 3;

  floatx4 acc[4][4];
#pragma unroll
  for (int i = 0; i < 4; ++i)
#pragma unroll
    for (int j = 0; j < 4; ++j) acc[i][j] = (floatx4){0.f, 0.f, 0.f, 0.f};

  for (int kt = 0; kt < K; kt += 64) {
#pragma unroll
    for (int i = 0; i < 4; ++i) {
      const unsigned short* ga = A + (size_t)(m0 + w * 32 + i * 8 + srow) * K + kt + scol;
      const unsigned short* gb = Bt + (size_t)(n0 + w * 32 + i * 8 + srow) * K + kt + scol;
      GLD_LDS16(ga, &As[w * 2048 + i * 512]);
      GLD_LDS16(gb, &Bs[w * 2048 + i * 512]);
    }
    __syncthreads();
#pragma unroll
    for (int ks = 0; ks < 2; ++ks) {
      const int rs = ((ks * 4 + quad) ^ (lm & 7)) << 3;   // read slot (free: 2/bank)
      short8 a[4], b[4];
#pragma unroll
      for (int i = 0; i < 4; ++i) a[i] = *(const short8*)&As[(wm * 64 + i * 16 + lm) * 64 + rs];
#pragma unroll
      for (int j = 0; j < 4; ++j) b[j] = *(const short8*)&Bs[(wn * 64 + j * 16 + lm) * 64 + rs];
#pragma unroll
      for (int i = 0; i < 4; ++i)
#pragma unroll
        for (int j = 0; j < 4; ++j)
          acc[i][j] = __builtin_amdgcn_mfma_f32_16x16x32_bf16(a[i], b[j], acc[i][j], 0, 0, 0);
    }
    __syncthreads();
  }

  if (n0 < 2048) {
    unsigned short* p = (n0 < 1024) ? oQ : oK;
    const float qscale = (n0 < 1024) ? 0.18033688f : 1.0f;   // 0.125*log2(e)
#pragma unroll
    for (int i = 0; i < 4; ++i) {
      int gmb = m0 + wm * 64 + i * 16 + quad * 4;
#pragma unroll
      for (int j = 0; j < 4; ++j) {
        int gn = n0 + wn * 64 + j * 16 + lm;
        int nn = gn & 1023, hh = nn >> 6, dd = nn & 63;
#pragma unroll
        for (int r = 0; r < 4; ++r) {
          int gm = gmb + r;
          int bb = gm >> 10, tt = gm & 1023;
          p[(((size_t)bb * H_ + hh) * T_ + tt) * DH_ + dd] = f2bf(acc[i][j][r] * qscale);
        }
      }
    }
  } else {
#pragma unroll
    for (int i = 0; i < 4; ++i) {
#pragma unroll
      for (int j = 0; j < 4; ++j) {
        int gn = n0 + wn * 64 + j * 16 + lm;
        int hd = (gn >> 6) & 1, dd = gn & 63;
        int kperm = quad * 32 + (wm * 4 + i) * 4;
        union { _Float16 h[4]; uint2 u; } pk;
#pragma unroll
        for (int r = 0; r < 4; ++r) pk.h[r] = (_Float16)acc[i][j][r];
        *(uint2*)&Cs[((size_t)(hd * 64 + dd)) * 136 + kperm] = pk.u;
      }
    }
    __syncthreads();
    const int row = t >> 1, half = t & 1;
    const int hd = row >> 6, dd = row & 63;
    const int hh = ((n0 & 1023) >> 6) + hd;
    const int bb = m0 >> 10, kbg = (m0 >> 7) & 7;
    const _Float16* srcp = &Cs[(size_t)(hd * 64 + dd) * 136 + half * 64];
    _Float16* dstp = oV + ((((size_t)bb * H_ + hh) * DH_ + dd) * 8 + kbg) * 128 + half * 64;
#pragma unroll
    for (int g = 0; g < 8; ++g)
      *(uint4*)(dstp + g * 8) = *(const uint4*)(srcp + g * 8);
  }
}

// ------------------------------------------------------------ FFN GEMM 64x128
// BK=64 (barriers 16). MODE 1: relu->bf16. MODE 2: plain->bf16.
template <int MODE>
__global__ __launch_bounds__(256, 2)
void gemm_ffn(const unsigned short* __restrict__ A,
              const unsigned short* __restrict__ Bt,
              unsigned short* __restrict__ oBf,
              const float* __restrict__ bias) {
  const int K = 1024, N = 1024;
  __shared__ __align__(16) unsigned short As[64 * 64];    // 8KB
  __shared__ __align__(16) unsigned short Bs[128 * 64];   // 16KB
  const int t = threadIdx.x;
  const int lane = t & 63, w = t >> 6;
  const int quad = lane >> 4, lm = lane & 15;
  const int wm = w >> 1, wn = w & 1;
  const int m0 = blockIdx.y * 64, n0 = blockIdx.x * 128;
  const int srow = lane >> 3;
  const int scol = ((lane & 7) ^ srow) << 3;

  floatx4 acc[2][4];
#pragma unroll
  for (int i = 0; i < 2; ++i)
#pragma unroll
    for (int j = 0; j < 4; ++j) acc[i][j] = (floatx4){0.f, 0.f, 0.f, 0.f};

  for (int kt = 0; kt < K; kt += 64) {
#pragma unroll
    for (int i = 0; i < 2; ++i) {
      const unsigned short* ga = A + (size_t)(m0 + w * 16 + i * 8 + srow) * K + kt + scol;
      GLD_LDS16(ga, &As[w * 1024 + i * 512]);
    }
#pragma unroll
    for (int i = 0; i < 4; ++i) {
      const unsigned short* gb = Bt + (size_t)(n0 + w * 32 + i * 8 + srow) * K + kt + scol;
      GLD_LDS16(gb, &Bs[w * 2048 + i * 512]);
    }
    __syncthreads();
#pragma unroll
    for (int ks = 0; ks < 2; ++ks) {
      const int rs = ((ks * 4 + quad) ^ (lm & 7)) << 3;
      short8 a[2], b[4];
#pragma unroll
      for (int i = 0; i < 2; ++i) a[i] = *(const short8*)&As[(wm * 32 + i * 16 + lm) * 64 + rs];
#pragma unroll
      for (int j = 0; j < 4; ++j) b[j] = *(const short8*)&Bs[(wn * 64 + j * 16 + lm) * 64 + rs];
#pragma unroll
      for (int i = 0; i < 2; ++i)
#pragma unroll
        for (int j = 0; j < 4; ++j)
          acc[i][j] = __builtin_amdgcn_mfma_f32_16x16x32_bf16(a[i], b[j], acc[i][j], 0, 0, 0);
    }
    __syncthreads();
  }

#pragma unroll
  for (int i = 0; i < 2; ++i) {
    int gmb = m0 + wm * 32 + i * 16 + quad * 4;
#pragma unroll
    for (int j = 0; j < 4; ++j) {
      int gn = n0 + wn * 64 + j * 16 + lm;
      float bv = bias[gn];
#pragma unroll
      for (int r = 0; r < 4; ++r) {
        int gm = gmb + r;
        float v = acc[i][j][r] + bv;
        if (MODE == 1) v = fmaxf(v, 0.f);
        oBf[(size_t)gm * N + gn] = f2bf(v);
      }
    }
  }
}

// --------------------------------------------------------------- flash attn
// 512 blocks x 256 thr; R12 decode; K+V LDS double-buffered (R14).
__global__ __launch_bounds__(256)
void flash_attn(const unsigned short* __restrict__ Qb,
                const unsigned short* __restrict__ Kb,
                const _Float16* __restrict__ Vtg,
                const float* __restrict__ maskp,
                unsigned short* __restrict__ attn) {
  __shared__ __align__(16) unsigned short KLs[2][8192];  // 2 x 16 KB
  __shared__ __align__(16) _Float16      VLs[2][8192];   // 2 x 16 KB

  const int t = threadIdx.x;
  const int lane = t & 63, w = t >> 6;
  const int quad = lane >> 4, lm = lane & 15;

  const int bid = blockIdx.x;               // 0..511
  const int hi  = bid >> 8;                 // 0/1: co-residency half
  const int lo  = bid & 255;
  const int xcd = lo & 7;
  const int hgrp = (lo >> 3) & 7;
  const int qpair = lo >> 6;                // 0..3
  const int qb = hi ? (7 - qpair) : qpair;  // pair (p, 7-p) share a CU
  const int head = hgrp * 8 + xcd;          // 0..63; head%8 = XCD
  const int hh = head & 15, bb = head >> 4;
  const int q0 = qb << 7;

  const size_t headoff = ((size_t)bb * H_ + hh) * T_ * DH_;
  const unsigned short* Qh = Qb + headoff;
  const unsigned short* Kh = Kb + headoff;
  const _Float16* Vh = Vtg + headoff;   // k-shuffled [d][kb][quad][j][r]

  short8 qf[2][2];
#pragma unroll
  for (int qg = 0; qg < 2; ++qg)
#pragma unroll
    for (int ks = 0; ks < 2; ++ks)
      qf[qg][ks] = *(const short8*)(Qh + (size_t)(q0 + w * 32 + qg * 16 + lm) * 64 + ks * 32 + quad * 8);

  float lsum[2] = {0.f, 0.f};
  floatx4 acc[2][4];
#pragma unroll
  for (int qg = 0; qg < 2; ++qg)
#pragma unroll
    for (int j2 = 0; j2 < 4; ++j2) acc[qg][j2] = (floatx4){0.f, 0.f, 0.f, 0.f};

  const int qglob0 = q0 + w * 32 + lm;
  const bool excl1 = (qglob0 + 16 == 1023);   // row-1023 lane (qg=1 only)
  const float MSHIFT = 14426.950408f;          // 10000*log2(e)

  const int my_lo  = (qb == 7 && w == 3) ? 0 : qb;  // this wave's first kb
  const int blk_lo = (qb == 7) ? 0 : qb;            // block staging range

  // per-wave staging source addresses (slots s = w*4 .. w*4+3)
  const unsigned short* gk[4];
  const _Float16* gv[4];
#pragma unroll
  for (int i = 0; i < 4; ++i) {
    int s = w * 4 + i;
    gk[i] = Kh + (size_t)((s >> 1) * 16 + lm) * 64 + (s & 1) * 32 + quad * 8;
    gv[i] = Vh + ((size_t)((s >> 2) * 16 + lm) * 8) * 128 + quad * 32 + (s & 3) * 8;
  }

  // prologue: stage blk_lo into buffer 0
#pragma unroll
  for (int i = 0; i < 4; ++i) {
    int s = w * 4 + i;
    GLD_LDS16(gk[i] + (size_t)blk_lo * 8192, &KLs[0][s * 512]);
    GLD_LDS16(gv[i] + (size_t)blk_lo * 128,  &VLs[0][s * 512]);
  }

  int cur = 0;
  for (int kb = blk_lo; kb < 8; ++kb) {
    __syncthreads();   // drains vmcnt -> staged buffer [cur] is ready
    if (kb + 1 < 8) {
      int nxt = cur ^ 1;
#pragma unroll
      for (int i = 0; i < 4; ++i) {
        int s = w * 4 + i;
        GLD_LDS16(gk[i] + (size_t)(kb + 1) * 8192, &KLs[nxt][s * 512]);
        GLD_LDS16(gv[i] + (size_t)(kb + 1) * 128,  &VLs[nxt][s * 512]);
      }
    }
    if (kb >= my_lo) {
      const unsigned short* Kc = &KLs[cur][0];
      const _Float16* Vc = &VLs[cur][0];
      const int k0 = kb * 128;
      const bool need_mask = (kb <= qb);

      // prefetch j=0 fragments
      short8 kA = *(const short8*)&Kc[(0 * 64 + lane) * 8];
      short8 kB = *(const short8*)&Kc[(1 * 64 + lane) * 8];
      half4 vA0 = *(const half4*)&Vc[((0 * 4 + 0) * 64 + lane) * 8];
      half4 vA1 = *(const half4*)&Vc[((1 * 4 + 0) * 64 + lane) * 8];
      half4 vA2 = *(const half4*)&Vc[((2 * 4 + 0) * 64 + lane) * 8];
      half4 vA3 = *(const half4*)&Vc[((3 * 4 + 0) * 64 + lane) * 8];

#pragma unroll
      for (int j = 0; j < 8; ++j) {
        short8 nA, nB; half4 n0, n1, n2, n3;
        if (j < 7) {
          int jn = j + 1;
          nA = *(const short8*)&Kc[((jn * 2 + 0) * 64 + lane) * 8];
          nB = *(const short8*)&Kc[((jn * 2 + 1) * 64 + lane) * 8];
          n0 = *(const half4*)&Vc[((0 * 4 + (jn >> 1)) * 64 + lane) * 8 + (jn & 1) * 4];
          n1 = *(const half4*)&Vc[((1 * 4 + (jn >> 1)) * 64 + lane) * 8 + (jn & 1) * 4];
          n2 = *(const half4*)&Vc[((2 * 4 + (jn >> 1)) * 64 + lane) * 8 + (jn & 1) * 4];
          n3 = *(const half4*)&Vc[((3 * 4 + (jn >> 1)) * 64 + lane) * 8 + (jn & 1) * 4];
        }
        // S-MFMAs
        floatx4 st[2];
#pragma unroll
        for (int qg = 0; qg < 2; ++qg) {
          floatx4 z = (floatx4){0.f, 0.f, 0.f, 0.f};
          z = __builtin_amdgcn_mfma_f32_16x16x32_bf16(kA, qf[qg][0], z, 0, 0, 0);
          st[qg] = __builtin_amdgcn_mfma_f32_16x16x32_bf16(kB, qf[qg][1], z, 0, 0, 0);
        }
        // softmax j
        half4 pa[2];
#pragma unroll
        for (int qg = 0; qg < 2; ++qg) {
          const int qq = qglob0 + qg * 16;
          const bool skip = (qg == 1) && excl1;
#pragma unroll
          for (int r = 0; r < 4; ++r) {
            int kg = k0 + j * 16 + quad * 4 + r;
            float v = st[qg][r];
            if (need_mask && !skip && kg <= qq) v -= MSHIFT;
            float p = __builtin_amdgcn_exp2f(v);
            lsum[qg] += p;
            pa[qg][r] = (_Float16)p;
          }
        }
        // PV j
        acc[0][0] = __builtin_amdgcn_mfma_f32_16x16x16f16(pa[0], vA0, acc[0][0], 0, 0, 0);
        acc[1][0] = __builtin_amdgcn_mfma_f32_16x16x16f16(pa[1], vA0, acc[1][0], 0, 0, 0);
        acc[0][1] = __builtin_amdgcn_mfma_f32_16x16x16f16(pa[0], vA1, acc[0][1], 0, 0, 0);
        acc[1][1] = __builtin_amdgcn_mfma_f32_16x16x16f16(pa[1], vA1, acc[1][1], 0, 0, 0);
        acc[0][2] = __builtin_amdgcn_mfma_f32_16x16x16f16(pa[0], vA2, acc[0][2], 0, 0, 0);
        acc[1][2] = __builtin_amdgcn_mfma_f32_16x16x16f16(pa[1], vA2, acc[1][2], 0, 0, 0);
        acc[0][3] = __builtin_amdgcn_mfma_f32_16x16x16f16(pa[0], vA3, acc[0][3], 0, 0, 0);
        acc[1][3] = __builtin_amdgcn_mfma_f32_16x16x16f16(pa[1], vA3, acc[1][3], 0, 0, 0);
        // rotate prefetched fragments
        kA = nA; kB = nB; vA0 = n0; vA1 = n1; vA2 = n2; vA3 = n3;
      }
    }
    cur ^= 1;
  }

  // epilogue
#pragma unroll
  for (int qg = 0; qg < 2; ++qg) {
    float l = lsum[qg];
    l += __shfl_xor(l, 16);
    l += __shfl_xor(l, 32);
    float s = maskp[bb * T_ + qglob0 + qg * 16] / l;
#pragma unroll
    for (int r = 0; r < 4; ++r) {
      float bsc = __shfl(s, quad * 4 + r);
      int tq = q0 + w * 32 + qg * 16 + quad * 4 + r;
#pragma unroll
      for (int j2 = 0; j2 < 4; ++j2)
        attn[((size_t)(bb * T_ + tq)) * D_ + hh * 64 + j2 * 16 + lm] = f2bf(acc[qg][j2][r] * bsc);
    }
  }
}

// ------------------- LN(xb_bf16 + attn_bf16) -> h1b bf16 (wave-per-row)
__global__ __launch_bounds__(256)
void ln_res_kernel(const unsigned short* __restrict__ xb, const unsigned short* __restrict__ attn,
                   const float* __restrict__ sc, const float* __restrict__ bi,
                   unsigned short* __restrict__ hb) {
  const int t = threadIdx.x;
  const int lane = t & 63, w = t >> 6;
  const int row = blockIdx.x * 4 + w;
  const size_t base = (size_t)row * D_ + lane * 16;

  float v[16];
  float s1 = 0.f, s2 = 0.f;
#pragma unroll
  for (int i = 0; i < 4; ++i) {
    union { uint2 u; unsigned short s[4]; } xu, au;
    xu.u = *(const uint2*)&xb[base + i * 4];
    au.u = *(const uint2*)&attn[base + i * 4];
    float x0 = bf2f(xu.s[0]) + bf2f(au.s[0]);
    float x1 = bf2f(xu.s[1]) + bf2f(au.s[1]);
    float x2 = bf2f(xu.s[2]) + bf2f(au.s[2]);
    float x3 = bf2f(xu.s[3]) + bf2f(au.s[3]);
    v[i * 4 + 0] = x0; v[i * 4 + 1] = x1; v[i * 4 + 2] = x2; v[i * 4 + 3] = x3;
    s1 += x0 + x1 + x2 + x3;
    s2 += x0 * x0 + x1 * x1 + x2 * x2 + x3 * x3;
  }
#pragma unroll
  for (int off = 1; off < 64; off <<= 1) {
    s1 += __shfl_xor(s1, off);
    s2 += __shfl_xor(s2, off);
  }
  float mean = s1 * (1.f / 1024.f);
  float var = s2 * (1.f / 1024.f) - mean * mean;
  float rstd = rsqrtf(var + 1e-5f);
#pragma unroll
  for (int i = 0; i < 4; ++i) {
    float4 sv = *(const float4*)&sc[lane * 16 + i * 4];
    float4 bv = *(const float4*)&bi[lane * 16 + i * 4];
    float o0 = (v[i * 4 + 0] - mean) * rstd * sv.x + bv.x;
    float o1 = (v[i * 4 + 1] - mean) * rstd * sv.y + bv.y;
    float o2 = (v[i * 4 + 2] - mean) * rstd * sv.z + bv.z;
    float o3 = (v[i * 4 + 3] - mean) * rstd * sv.w + bv.w;
    union { uint2 u; unsigned short s[4]; } ob;
    ob.s[0] = f2bf(o0); ob.s[1] = f2bf(o1); ob.s[2] = f2bf(o2); ob.s[3] = f2bf(o3);
    *(uint2*)&hb[base + i * 4] = ob.u;
  }
}

// ---------------- out = LN(LN(h1b+ffnb,ln2),ln3) (wave-per-row, both bf16)
__global__ __launch_bounds__(256)
void ln_double_kernel(const unsigned short* __restrict__ h1b,
                      const unsigned short* __restrict__ ffnb,
                      const float* __restrict__ s2c, const float* __restrict__ b2c,
                      const float* __restrict__ s3c, const float* __restrict__ b3c,
                      float* __restrict__ out) {
  const int t = threadIdx.x;
  const int lane = t & 63, w = t >> 6;
  const int row = blockIdx.x * 4 + w;
  const size_t base = (size_t)row * D_ + lane * 16;

  float v[16];
  float s1 = 0.f, s2 = 0.f;
#pragma unroll
  for (int i = 0; i < 4; ++i) {
    union { uint2 u; unsigned short s[4]; } hu, fu;
    hu.u = *(const uint2*)&h1b[base + i * 4];
    fu.u = *(const uint2*)&ffnb[base + i * 4];
    float x0 = bf2f(hu.s[0]) + bf2f(fu.s[0]);
    float x1 = bf2f(hu.s[1]) + bf2f(fu.s[1]);
    float x2 = bf2f(hu.s[2]) + bf2f(fu.s[2]);
    float x3 = bf2f(hu.s[3]) + bf2f(fu.s[3]);
    v[i * 4 + 0] = x0; v[i * 4 + 1] = x1; v[i * 4 + 2] = x2; v[i * 4 + 3] = x3;
    s1 += x0 + x1 + x2 + x3;
    s2 += x0 * x0 + x1 * x1 + x2 * x2 + x3 * x3;
  }
#pragma unroll
  for (int off = 1; off < 64; off <<= 1) {
    s1 += __shfl_xor(s1, off);
    s2 += __shfl_xor(s2, off);
  }
  float mean = s1 * (1.f / 1024.f);
  float var = s2 * (1.f / 1024.f) - mean * mean;
  float rstd = rsqrtf(var + 1e-5f);

  float o[16];
  float u1 = 0.f, u2 = 0.f;
#pragma unroll
  for (int i = 0; i < 4; ++i) {
    float4 sv = *(const float4*)&s2c[lane * 16 + i * 4];
    float4 bv = *(const float4*)&b2c[lane * 16 + i * 4];
    float o0 = (v[i * 4 + 0] - mean) * rstd * sv.x + bv.x;
    float o1 = (v[i * 4 + 1] - mean) * rstd * sv.y + bv.y;
    float o2 = (v[i * 4 + 2] - mean) * rstd * sv.z + bv.z;
    float o3 = (v[i * 4 + 3] - mean) * rstd * sv.w + bv.w;
    o[i * 4 + 0] = o0; o[i * 4 + 1] = o1; o[i * 4 + 2] = o2; o[i * 4 + 3] = o3;
    u1 += o0 + o1 + o2 + o3;
    u2 += o0 * o0 + o1 * o1 + o2 * o2 + o3 * o3;
  }
#pragma unroll
  for (int off = 1; off < 64; off <<= 1) {
    u1 += __shfl_xor(u1, off);
    u2 += __shfl_xor(u2, off);
  }
  float mean2 = u1 * (1.f / 1024.f);
  float var2 = u2 * (1.f / 1024.f) - mean2 * mean2;
  float rstd2 = rsqrtf(var2 + 1e-5f);
#pragma unroll
  for (int i = 0; i < 4; ++i) {
    float4 sv = *(const float4*)&s3c[lane * 16 + i * 4];
    float4 bv = *(const float4*)&b3c[lane * 16 + i * 4];
    float4 fo;
    fo.x = (o[i * 4 + 0] - mean2) * rstd2 * sv.x + bv.x;
    fo.y = (o[i * 4 + 1] - mean2) * rstd2 * sv.y + bv.y;
    fo.z = (o[i * 4 + 2] - mean2) * rstd2 * sv.z + bv.z;
    fo.w = (o[i * 4 + 3] - mean2) * rstd2 * sv.w + bv.w;
    *(float4*)&out[base + i * 4] = fo;
  }
}

// ------------------------------------------------------------------ launch
extern "C" void kernel_launch(void* const* d_in, const int* in_sizes, int n_in,
                              void* d_out, int out_size, void* d_ws, size_t ws_size,
                              hipStream_t stream) {
  (void)in_sizes; (void)n_in; (void)out_size; (void)ws_size;
  const float* x   = (const float*)d_in[0];
  const float* msk = (const float*)d_in[1];
  const float* wq  = (const float*)d_in[2];
  const float* wk  = (const float*)d_in[3];
  const float* wv  = (const float*)d_in[4];
  const float* w1  = (const float*)d_in[5];
  const float* b1  = (const float*)d_in[6];
  const float* w2  = (const float*)d_in[7];
  const float* b2  = (const float*)d_in[8];
  const float* l1s = (const float*)d_in[9];
  const float* l1b = (const float*)d_in[10];
  const float* l2s = (const float*)d_in[11];
  const float* l2b = (const float*)d_in[12];
  const float* l3s = (const float*)d_in[13];
  const float* l3b = (const float*)d_in[14];
  float* outp = (float*)d_out;

  char* ws = (char*)d_ws;
  unsigned short* xb   = (unsigned short*)(ws);                       // 8 MB (live thru ln_res)
  unsigned short* wt   = (unsigned short*)(ws + ((size_t)8  << 20));  // 10 MB
  unsigned short* Qb   = (unsigned short*)(ws + ((size_t)18 << 20));  // 8 MB [B,H,T,DH]
  unsigned short* Kb   = (unsigned short*)(ws + ((size_t)26 << 20));  // 8 MB
  _Float16*       Vtg  = (_Float16*)(ws + ((size_t)34 << 20));        // 8 MB k-shuffled V^T
  unsigned short* attn = (unsigned short*)(ws + ((size_t)42 << 20));  // 8 MB bf16 [B,T,D]
  unsigned short* h1b  = (unsigned short*)(ws + ((size_t)18 << 20));  // reuse Qb (8 MB bf16)
  unsigned short* gb   = (unsigned short*)(ws + ((size_t)26 << 20));  // reuse Kb
  unsigned short* ffnb = (unsigned short*)(ws + ((size_t)34 << 20));  // reuse Vtg (8 MB bf16)

  prep_kernel<<<1024 + 1280, 256, 0, stream>>>((const float4*)x, xb,
                                               wq, wk, wv, w1, w2, wt);
  gemm_qkv<<<dim3(24, 32), 256, 0, stream>>>(xb, wt, Qb, Kb, Vtg);
  flash_attn<<<512, 256, 0, stream>>>(Qb, Kb, Vtg, msk, attn);
  ln_res_kernel<<<1024, 256, 0, stream>>>(xb, attn, l1s, l1b, h1b);
  gemm_ffn<1><<<dim3(8, 64), 256, 0, stream>>>(h1b, wt + (size_t)3 * 1024 * 1024, gb, b1);
  gemm_ffn<2><<<dim3(8, 64), 256, 0, stream>>>(gb, wt + (size_t)4 * 1024 * 1024, ffnb, b2);
  ln_double_kernel<<<1024, 256, 0, stream>>>(h1b, ffnb, l2s, l2b, l3s, l3b, outp);
}

// Round 12
// 215.164 us; speedup vs baseline: 1.0991x; 1.0321x over previous
//
#include <hip/hip_runtime.h>
#include <stdint.h>

// B=4, T=1024, D=1024, H=16, DH=64. fp32 in/out, absmax thr 0.1.
// R20 vs R19: flash TLP fix. R19 counters re-exposed flash as the largest
// controllable kernel (44.9us, Mfma 11.6%, occ 14.5%): after the short
// partner block retires, the long block's ~7 rounds run at 4 waves/CU =
// 1 wave/SIMD. R13's wave-doubling failed because waves privately re-read
// K from global; R14's LDS staging made K/V per-BLOCK, so doubling waves
// is now free of extra global traffic. R20: 512-thread blocks, 8 waves x
// 16 q-rows (1 qg), same 512-block grid + R12 pairing + staging layout
// (32 slots = 4/wave over 8 waves; compute-side reads unchanged). Tail
// TLP 1 -> 2 waves/SIMD; per-wave VGPR ~88 -> ~65. Plain
// __launch_bounds__(512) — NO min-waves arg (R9: (512,4) forced 64 VGPR
// and spilled catastrophically). Everything else byte-identical to R19.

#define B_  4
#define T_  1024
#define D_  1024
#define H_  16
#define DH_ 64

typedef __attribute__((ext_vector_type(8))) short short8;
typedef __attribute__((ext_vector_type(4))) float floatx4;
typedef __attribute__((ext_vector_type(4))) _Float16 half4;

__device__ __forceinline__ unsigned short f2bf(float f) {
  union { float f; uint32_t u; } a; a.f = f;
  uint32_t r = a.u + 0x7FFFu + ((a.u >> 16) & 1u);
  return (unsigned short)(r >> 16);
}
__device__ __forceinline__ float bf2f(unsigned short u) {
  union { uint32_t u; float f; } a; a.u = ((uint32_t)u) << 16;
  return a.f;
}

#define GLD_LDS16(g, l) __builtin_amdgcn_global_load_lds( \
    (const __attribute__((address_space(1))) unsigned int*)(g), \
    (__attribute__((address_space(3))) unsigned int*)(l), 16, 0, 0)

// ---------------------------------------------- prep: cast x + transpose W
__global__ __launch_bounds__(256)
void prep_kernel(const float4* __restrict__ x4, unsigned short* __restrict__ xb,
                 const float* __restrict__ w0, const float* __restrict__ w1,
                 const float* __restrict__ w2, const float* __restrict__ w3,
                 const float* __restrict__ w4, unsigned short* __restrict__ dst_all) {
  const int t = threadIdx.x;
  if (blockIdx.x < 1024) {
    int idx0 = blockIdx.x * 1024 + t;
#pragma unroll
    for (int c = 0; c < 4; ++c) {
      int idx = idx0 + c * 256;
      float4 v = x4[idx];
      union { uint2 u; unsigned short s[4]; } o;
      o.s[0] = f2bf(v.x); o.s[1] = f2bf(v.y); o.s[2] = f2bf(v.z); o.s[3] = f2bf(v.w);
      *(uint2*)&xb[(size_t)idx * 4] = o.u;
    }
    return;
  }
  const int b = blockIdx.x - 1024;
  const int z = b >> 8, ky = (b >> 4) & 15, nx = b & 15;
  const float* src = (z == 0) ? w0 : (z == 1) ? w1 : (z == 2) ? w2 : (z == 3) ? w3 : w4;
  unsigned short* dst = dst_all + (size_t)z * D_ * D_;
  __shared__ __align__(16) unsigned short tile[64 * 72];
  const int k0 = ky * 64, n0 = nx * 64;
#pragma unroll
  for (int c = 0; c < 4; ++c) {
    int idx = c * 256 + t;
    int r = idx >> 4, cc = (idx & 15) << 2;
    float4 v = *(const float4*)&src[(size_t)(k0 + r) * D_ + n0 + cc];
    tile[(cc + 0) * 72 + r] = f2bf(v.x);
    tile[(cc + 1) * 72 + r] = f2bf(v.y);
    tile[(cc + 2) * 72 + r] = f2bf(v.z);
    tile[(cc + 3) * 72 + r] = f2bf(v.w);
  }
  __syncthreads();
  int rr = t >> 2, ck = (t & 3) << 4;
  uint4 v0 = *(const uint4*)&tile[rr * 72 + ck];
  uint4 v1 = *(const uint4*)&tile[rr * 72 + ck + 8];
  *(uint4*)&dst[(size_t)(n0 + rr) * D_ + k0 + ck] = v0;
  *(uint4*)&dst[(size_t)(n0 + rr) * D_ + k0 + ck + 8] = v1;
}

// ------------------------------------------------------------------ QKV GEMM
// BK=64, Cs overlaid on As+Bs (LDS 34816B -> 3 blocks/CU at grid 768).
__global__ __launch_bounds__(256, 2)
void gemm_qkv(const unsigned short* __restrict__ A,
              const unsigned short* __restrict__ Bt,
              unsigned short* __restrict__ oQ, unsigned short* __restrict__ oK,
              _Float16* __restrict__ oV) {
  const int K = 1024;
  __shared__ __align__(16) unsigned char smem[34816];   // max(As+Bs=32KB, Cs=34KB)
  unsigned short* As = (unsigned short*)smem;           // 128x64 = 16KB
  unsigned short* Bs = (unsigned short*)(smem + 16384); // 128x64 = 16KB
  _Float16* Cs = (_Float16*)smem;                       // 2*64*136 (post-loop)
  const int t = threadIdx.x;
  const int lane = t & 63, w = t >> 6;
  const int quad = lane >> 4, lm = lane & 15;
  const int wm = w >> 1, wn = w & 1;
  const int m0 = blockIdx.y * 128, n0 = blockIdx.x * 128;
  // staging: lane l covers row i*8+(l>>3) of its wave's 32-row strip,
  // LDS slot (l&7); global chunk = (l&7)^((l>>3)&7)  [row key = row&7]
  const int srow = lane >> 3;
  const int scol = ((lane & 7) ^ srow) << 3;

  floatx4 acc[4][4];
#pragma unroll
  for (int i = 0; i < 4; ++i)
#pragma unroll
    for (int j = 0; j < 4; ++j) acc[i][j] = (floatx4){0.f, 0.f, 0.f, 0.f};

  for (int kt = 0; kt < K; kt += 64) {
#pragma unroll
    for (int i = 0; i < 4; ++i) {
      const unsigned short* ga = A + (size_t)(m0 + w * 32 + i * 8 + srow) * K + kt + scol;
      const unsigned short* gb = Bt + (size_t)(n0 + w * 32 + i * 8 + srow) * K + kt + scol;
      GLD_LDS16(ga, &As[w * 2048 + i * 512]);
      GLD_LDS16(gb, &Bs[w * 2048 + i * 512]);
    }
    __syncthreads();
#pragma unroll
    for (int ks = 0; ks < 2; ++ks) {
      const int rs = ((ks * 4 + quad) ^ (lm & 7)) << 3;   // read slot (free: 2/bank)
      short8 a[4], b[4];
#pragma unroll
      for (int i = 0; i < 4; ++i) a[i] = *(const short8*)&As[(wm * 64 + i * 16 + lm) * 64 + rs];
#pragma unroll
      for (int j = 0; j < 4; ++j) b[j] = *(const short8*)&Bs[(wn * 64 + j * 16 + lm) * 64 + rs];
#pragma unroll
      for (int i = 0; i < 4; ++i)
#pragma unroll
        for (int j = 0; j < 4; ++j)
          acc[i][j] = __builtin_amdgcn_mfma_f32_16x16x32_bf16(a[i], b[j], acc[i][j], 0, 0, 0);
    }
    __syncthreads();
  }

  if (n0 < 2048) {
    unsigned short* p = (n0 < 1024) ? oQ : oK;
    const float qscale = (n0 < 1024) ? 0.18033688f : 1.0f;   // 0.125*log2(e)
#pragma unroll
    for (int i = 0; i < 4; ++i) {
      int gmb = m0 + wm * 64 + i * 16 + quad * 4;
#pragma unroll
      for (int j = 0; j < 4; ++j) {
        int gn = n0 + wn * 64 + j * 16 + lm;
        int nn = gn & 1023, hh = nn >> 6, dd = nn & 63;
#pragma unroll
        for (int r = 0; r < 4; ++r) {
          int gm = gmb + r;
          int bb = gm >> 10, tt = gm & 1023;
          p[(((size_t)bb * H_ + hh) * T_ + tt) * DH_ + dd] = f2bf(acc[i][j][r] * qscale);
        }
      }
    }
  } else {
#pragma unroll
    for (int i = 0; i < 4; ++i) {
#pragma unroll
      for (int j = 0; j < 4; ++j) {
        int gn = n0 + wn * 64 + j * 16 + lm;
        int hd = (gn >> 6) & 1, dd = gn & 63;
        int kperm = quad * 32 + (wm * 4 + i) * 4;
        union { _Float16 h[4]; uint2 u; } pk;
#pragma unroll
        for (int r = 0; r < 4; ++r) pk.h[r] = (_Float16)acc[i][j][r];
        *(uint2*)&Cs[((size_t)(hd * 64 + dd)) * 136 + kperm] = pk.u;
      }
    }
    __syncthreads();
    const int row = t >> 1, half = t & 1;
    const int hd = row >> 6, dd = row & 63;
    const int hh = ((n0 & 1023) >> 6) + hd;
    const int bb = m0 >> 10, kbg = (m0 >> 7) & 7;
    const _Float16* srcp = &Cs[(size_t)(hd * 64 + dd) * 136 + half * 64];
    _Float16* dstp = oV + ((((size_t)bb * H_ + hh) * DH_ + dd) * 8 + kbg) * 128 + half * 64;
#pragma unroll
    for (int g = 0; g < 8; ++g)
      *(uint4*)(dstp + g * 8) = *(const uint4*)(srcp + g * 8);
  }
}

// ------------------------------------------------------------ FFN GEMM 64x128
// BK=64 (barriers 16). MODE 1: relu->bf16. MODE 2: plain->bf16.
template <int MODE>
__global__ __launch_bounds__(256, 2)
void gemm_ffn(const unsigned short* __restrict__ A,
              const unsigned short* __restrict__ Bt,
              unsigned short* __restrict__ oBf,
              const float* __restrict__ bias) {
  const int K = 1024, N = 1024;
  __shared__ __align__(16) unsigned short As[64 * 64];    // 8KB
  __shared__ __align__(16) unsigned short Bs[128 * 64];   // 16KB
  const int t = threadIdx.x;
  const int lane = t & 63, w = t >> 6;
  const int quad = lane >> 4, lm = lane & 15;
  const int wm = w >> 1, wn = w & 1;
  const int m0 = blockIdx.y * 64, n0 = blockIdx.x * 128;
  const int srow = lane >> 3;
  const int scol = ((lane & 7) ^ srow) << 3;

  floatx4 acc[2][4];
#pragma unroll
  for (int i = 0; i < 2; ++i)
#pragma unroll
    for (int j = 0; j < 4; ++j) acc[i][j] = (floatx4){0.f, 0.f, 0.f, 0.f};

  for (int kt = 0; kt < K; kt += 64) {
#pragma unroll
    for (int i = 0; i < 2; ++i) {
      const unsigned short* ga = A + (size_t)(m0 + w * 16 + i * 8 + srow) * K + kt + scol;
      GLD_LDS16(ga, &As[w * 1024 + i * 512]);
    }
#pragma unroll
    for (int i = 0; i < 4; ++i) {
      const unsigned short* gb = Bt + (size_t)(n0 + w * 32 + i * 8 + srow) * K + kt + scol;
      GLD_LDS16(gb, &Bs[w * 2048 + i * 512]);
    }
    __syncthreads();
#pragma unroll
    for (int ks = 0; ks < 2; ++ks) {
      const int rs = ((ks * 4 + quad) ^ (lm & 7)) << 3;
      short8 a[2], b[4];
#pragma unroll
      for (int i = 0; i < 2; ++i) a[i] = *(const short8*)&As[(wm * 32 + i * 16 + lm) * 64 + rs];
#pragma unroll
      for (int j = 0; j < 4; ++j) b[j] = *(const short8*)&Bs[(wn * 64 + j * 16 + lm) * 64 + rs];
#pragma unroll
      for (int i = 0; i < 2; ++i)
#pragma unroll
        for (int j = 0; j < 4; ++j)
          acc[i][j] = __builtin_amdgcn_mfma_f32_16x16x32_bf16(a[i], b[j], acc[i][j], 0, 0, 0);
    }
    __syncthreads();
  }

#pragma unroll
  for (int i = 0; i < 2; ++i) {
    int gmb = m0 + wm * 32 + i * 16 + quad * 4;
#pragma unroll
    for (int j = 0; j < 4; ++j) {
      int gn = n0 + wn * 64 + j * 16 + lm;
      float bv = bias[gn];
#pragma unroll
      for (int r = 0; r < 4; ++r) {
        int gm = gmb + r;
        float v = acc[i][j][r] + bv;
        if (MODE == 1) v = fmaxf(v, 0.f);
        oBf[(size_t)gm * N + gn] = f2bf(v);
      }
    }
  }
}

// --------------------------------------------------------------- flash attn
// 512 blocks x 512 thr (8 waves x 16 q-rows, 1 qg); R12 decode; K+V LDS
// double-buffered (R14 layout; 32 slots = 4/wave). Wave 7 of qb==7 blocks
// loops kb=0..7 (row-1023 never masked).
__global__ __launch_bounds__(512)
void flash_attn(const unsigned short* __restrict__ Qb,
                const unsigned short* __restrict__ Kb,
                const _Float16* __restrict__ Vtg,
                const float* __restrict__ maskp,
                unsigned short* __restrict__ attn) {
  __shared__ __align__(16) unsigned short KLs[2][8192];  // 2 x 16 KB
  __shared__ __align__(16) _Float16      VLs[2][8192];   // 2 x 16 KB

  const int t = threadIdx.x;
  const int lane = t & 63, w = t >> 6;        // w: 0..7
  const int quad = lane >> 4, lm = lane & 15;

  const int bid = blockIdx.x;               // 0..511
  const int hi  = bid >> 8;                 // 0/1: co-residency half
  const int lo  = bid & 255;
  const int xcd = lo & 7;
  const int hgrp = (lo >> 3) & 7;
  const int qpair = lo >> 6;                // 0..3
  const int qb = hi ? (7 - qpair) : qpair;  // pair (p, 7-p) share a CU
  const int head = hgrp * 8 + xcd;          // 0..63; head%8 = XCD
  const int hh = head & 15, bb = head >> 4;
  const int q0 = qb << 7;

  const size_t headoff = ((size_t)bb * H_ + hh) * T_ * DH_;
  const unsigned short* Qh = Qb + headoff;
  const unsigned short* Kh = Kb + headoff;
  const _Float16* Vh = Vtg + headoff;   // k-shuffled [d][kb][quad][j][r]

  short8 qf[2];
#pragma unroll
  for (int ks = 0; ks < 2; ++ks)
    qf[ks] = *(const short8*)(Qh + (size_t)(q0 + w * 16 + lm) * 64 + ks * 32 + quad * 8);

  float lsum = 0.f;
  floatx4 acc[4];
#pragma unroll
  for (int j2 = 0; j2 < 4; ++j2) acc[j2] = (floatx4){0.f, 0.f, 0.f, 0.f};

  const int qglob = q0 + w * 16 + lm;         // this lane's q row
  const bool excl = (qglob == 1023);          // row-1023 lane: never masked
  const float MSHIFT = 14426.950408f;         // 10000*log2(e)

  const int my_lo  = (qb == 7 && w == 7) ? 0 : qb;  // this wave's first kb
  const int blk_lo = (qb == 7) ? 0 : qb;            // block staging range

  // per-wave staging source addresses (slots s = w*2, w*2+1 for K and V)
  const unsigned short* gk[2];
  const _Float16* gv[2];
#pragma unroll
  for (int i = 0; i < 2; ++i) {
    int s = w * 2 + i;
    gk[i] = Kh + (size_t)((s >> 1) * 16 + lm) * 64 + (s & 1) * 32 + quad * 8;
    gv[i] = Vh + ((size_t)((s >> 2) * 16 + lm) * 8) * 128 + quad * 32 + (s & 3) * 8;
  }

  // prologue: stage blk_lo into buffer 0
#pragma unroll
  for (int i = 0; i < 2; ++i) {
    int s = w * 2 + i;
    GLD_LDS16(gk[i] + (size_t)blk_lo * 8192, &KLs[0][s * 512]);
    GLD_LDS16(gv[i] + (size_t)blk_lo * 128,  &VLs[0][s * 512]);
  }

  int cur = 0;
  for (int kb = blk_lo; kb < 8; ++kb) {
    __syncthreads();   // drains vmcnt -> staged buffer [cur] is ready
    if (kb + 1 < 8) {
      int nxt = cur ^ 1;
#pragma unroll
      for (int i = 0; i < 2; ++i) {
        int s = w * 2 + i;
        GLD_LDS16(gk[i] + (size_t)(kb + 1) * 8192, &KLs[nxt][s * 512]);
        GLD_LDS16(gv[i] + (size_t)(kb + 1) * 128,  &VLs[nxt][s * 512]);
      }
    }
    if (kb >= my_lo) {
      const unsigned short* Kc = &KLs[cur][0];
      const _Float16* Vc = &VLs[cur][0];
      const int k0 = kb * 128;
      const bool need_mask = (kb <= qb);

      // prefetch j=0 fragments
      short8 kA = *(const short8*)&Kc[(0 * 64 + lane) * 8];
      short8 kB = *(const short8*)&Kc[(1 * 64 + lane) * 8];
      half4 vA0 = *(const half4*)&Vc[((0 * 4 + 0) * 64 + lane) * 8];
      half4 vA1 = *(const half4*)&Vc[((1 * 4 + 0) * 64 + lane) * 8];
      half4 vA2 = *(const half4*)&Vc[((2 * 4 + 0) * 64 + lane) * 8];
      half4 vA3 = *(const half4*)&Vc[((3 * 4 + 0) * 64 + lane) * 8];

#pragma unroll
      for (int j = 0; j < 8; ++j) {
        short8 nA, nB; half4 n0, n1, n2, n3;
        if (j < 7) {
          int jn = j + 1;
          nA = *(const short8*)&Kc[((jn * 2 + 0) * 64 + lane) * 8];
          nB = *(const short8*)&Kc[((jn * 2 + 1) * 64 + lane) * 8];
          n0 = *(const half4*)&Vc[((0 * 4 + (jn >> 1)) * 64 + lane) * 8 + (jn & 1) * 4];
          n1 = *(const half4*)&Vc[((1 * 4 + (jn >> 1)) * 64 + lane) * 8 + (jn & 1) * 4];
          n2 = *(const half4*)&Vc[((2 * 4 + (jn >> 1)) * 64 + lane) * 8 + (jn & 1) * 4];
          n3 = *(const half4*)&Vc[((3 * 4 + (jn >> 1)) * 64 + lane) * 8 + (jn & 1) * 4];
        }
        // S-MFMAs
        floatx4 st;
        {
          floatx4 z = (floatx4){0.f, 0.f, 0.f, 0.f};
          z = __builtin_amdgcn_mfma_f32_16x16x32_bf16(kA, qf[0], z, 0, 0, 0);
          st = __builtin_amdgcn_mfma_f32_16x16x32_bf16(kB, qf[1], z, 0, 0, 0);
        }
        // softmax j
        half4 pa;
#pragma unroll
        for (int r = 0; r < 4; ++r) {
          int kg = k0 + j * 16 + quad * 4 + r;
          float v = st[r];
          if (need_mask && !excl && kg <= qglob) v -= MSHIFT;
          float p = __builtin_amdgcn_exp2f(v);
          lsum += p;
          pa[r] = (_Float16)p;
        }
        // PV j
        acc[0] = __builtin_amdgcn_mfma_f32_16x16x16f16(pa, vA0, acc[0], 0, 0, 0);
        acc[1] = __builtin_amdgcn_mfma_f32_16x16x16f16(pa, vA1, acc[1], 0, 0, 0);
        acc[2] = __builtin_amdgcn_mfma_f32_16x16x16f16(pa, vA2, acc[2], 0, 0, 0);
        acc[3] = __builtin_amdgcn_mfma_f32_16x16x16f16(pa, vA3, acc[3], 0, 0, 0);
        // rotate prefetched fragments
        kA = nA; kB = nB; vA0 = n0; vA1 = n1; vA2 = n2; vA3 = n3;
      }
    }
    cur ^= 1;
  }

  // epilogue
  {
    float l = lsum;
    l += __shfl_xor(l, 16);
    l += __shfl_xor(l, 32);
    float s = maskp[bb * T_ + qglob] / l;
#pragma unroll
    for (int r = 0; r < 4; ++r) {
      float bsc = __shfl(s, quad * 4 + r);
      int tq = q0 + w * 16 + quad * 4 + r;
#pragma unroll
      for (int j2 = 0; j2 < 4; ++j2)
        attn[((size_t)(bb * T_ + tq)) * D_ + hh * 64 + j2 * 16 + lm] = f2bf(acc[j2][r] * bsc);
    }
  }
}

// ------------------- LN(xb_bf16 + attn_bf16) -> h1b bf16 (wave-per-row)
__global__ __launch_bounds__(256)
void ln_res_kernel(const unsigned short* __restrict__ xb, const unsigned short* __restrict__ attn,
                   const float* __restrict__ sc, const float* __restrict__ bi,
                   unsigned short* __restrict__ hb) {
  const int t = threadIdx.x;
  const int lane = t & 63, w = t >> 6;
  const int row = blockIdx.x * 4 + w;
  const size_t base = (size_t)row * D_ + lane * 16;

  float v[16];
  float s1 = 0.f, s2 = 0.f;
#pragma unroll
  for (int i = 0; i < 4; ++i) {
    union { uint2 u; unsigned short s[4]; } xu, au;
    xu.u = *(const uint2*)&xb[base + i * 4];
    au.u = *(const uint2*)&attn[base + i * 4];
    float x0 = bf2f(xu.s[0]) + bf2f(au.s[0]);
    float x1 = bf2f(xu.s[1]) + bf2f(au.s[1]);
    float x2 = bf2f(xu.s[2]) + bf2f(au.s[2]);
    float x3 = bf2f(xu.s[3]) + bf2f(au.s[3]);
    v[i * 4 + 0] = x0; v[i * 4 + 1] = x1; v[i * 4 + 2] = x2; v[i * 4 + 3] = x3;
    s1 += x0 + x1 + x2 + x3;
    s2 += x0 * x0 + x1 * x1 + x2 * x2 + x3 * x3;
  }
#pragma unroll
  for (int off = 1; off < 64; off <<= 1) {
    s1 += __shfl_xor(s1, off);
    s2 += __shfl_xor(s2, off);
  }
  float mean = s1 * (1.f / 1024.f);
  float var = s2 * (1.f / 1024.f) - mean * mean;
  float rstd = rsqrtf(var + 1e-5f);
#pragma unroll
  for (int i = 0; i < 4; ++i) {
    float4 sv = *(const float4*)&sc[lane * 16 + i * 4];
    float4 bv = *(const float4*)&bi[lane * 16 + i * 4];
    float o0 = (v[i * 4 + 0] - mean) * rstd * sv.x + bv.x;
    float o1 = (v[i * 4 + 1] - mean) * rstd * sv.y + bv.y;
    float o2 = (v[i * 4 + 2] - mean) * rstd * sv.z + bv.z;
    float o3 = (v[i * 4 + 3] - mean) * rstd * sv.w + bv.w;
    union { uint2 u; unsigned short s[4]; } ob;
    ob.s[0] = f2bf(o0); ob.s[1] = f2bf(o1); ob.s[2] = f2bf(o2); ob.s[3] = f2bf(o3);
    *(uint2*)&hb[base + i * 4] = ob.u;
  }
}

// ---------------- out = LN(LN(h1b+ffnb,ln2),ln3) (wave-per-row, both bf16)
__global__ __launch_bounds__(256)
void ln_double_kernel(const unsigned short* __restrict__ h1b,
                      const unsigned short* __restrict__ ffnb,
                      const float* __restrict__ s2c, const float* __restrict__ b2c,
                      const float* __restrict__ s3c, const float* __restrict__ b3c,
                      float* __restrict__ out) {
  const int t = threadIdx.x;
  const int lane = t & 63, w = t >> 6;
  const int row = blockIdx.x * 4 + w;
  const size_t base = (size_t)row * D_ + lane * 16;

  float v[16];
  float s1 = 0.f, s2 = 0.f;
#pragma unroll
  for (int i = 0; i < 4; ++i) {
    union { uint2 u; unsigned short s[4]; } hu, fu;
    hu.u = *(const uint2*)&h1b[base + i * 4];
    fu.u = *(const uint2*)&ffnb[base + i * 4];
    float x0 = bf2f(hu.s[0]) + bf2f(fu.s[0]);
    float x1 = bf2f(hu.s[1]) + bf2f(fu.s[1]);
    float x2 = bf2f(hu.s[2]) + bf2f(fu.s[2]);
    float x3 = bf2f(hu.s[3]) + bf2f(fu.s[3]);
    v[i * 4 + 0] = x0; v[i * 4 + 1] = x1; v[i * 4 + 2] = x2; v[i * 4 + 3] = x3;
    s1 += x0 + x1 + x2 + x3;
    s2 += x0 * x0 + x1 * x1 + x2 * x2 + x3 * x3;
  }
#pragma unroll
  for (int off = 1; off < 64; off <<= 1) {
    s1 += __shfl_xor(s1, off);
    s2 += __shfl_xor(s2, off);
  }
  float mean = s1 * (1.f / 1024.f);
  float var = s2 * (1.f / 1024.f) - mean * mean;
  float rstd = rsqrtf(var + 1e-5f);

  float o[16];
  float u1 = 0.f, u2 = 0.f;
#pragma unroll
  for (int i = 0; i < 4; ++i) {
    float4 sv = *(const float4*)&s2c[lane * 16 + i * 4];
    float4 bv = *(const float4*)&b2c[lane * 16 + i * 4];
    float o0 = (v[i * 4 + 0] - mean) * rstd * sv.x + bv.x;
    float o1 = (v[i * 4 + 1] - mean) * rstd * sv.y + bv.y;
    float o2 = (v[i * 4 + 2] - mean) * rstd * sv.z + bv.z;
    float o3 = (v[i * 4 + 3] - mean) * rstd * sv.w + bv.w;
    o[i * 4 + 0] = o0; o[i * 4 + 1] = o1; o[i * 4 + 2] = o2; o[i * 4 + 3] = o3;
    u1 += o0 + o1 + o2 + o3;
    u2 += o0 * o0 + o1 * o1 + o2 * o2 + o3 * o3;
  }
#pragma unroll
  for (int off = 1; off < 64; off <<= 1) {
    u1 += __shfl_xor(u1, off);
    u2 += __shfl_xor(u2, off);
  }
  float mean2 = u1 * (1.f / 1024.f);
  float var2 = u2 * (1.f / 1024.f) - mean2 * mean2;
  float rstd2 = rsqrtf(var2 + 1e-5f);
#pragma unroll
  for (int i = 0; i < 4; ++i) {
    float4 sv = *(const float4*)&s3c[lane * 16 + i * 4];
    float4 bv = *(const float4*)&b3c[lane * 16 + i * 4];
    float4 fo;
    fo.x = (o[i * 4 + 0] - mean2) * rstd2 * sv.x + bv.x;
    fo.y = (o[i * 4 + 1] - mean2) * rstd2 * sv.y + bv.y;
    fo.z = (o[i * 4 + 2] - mean2) * rstd2 * sv.z + bv.z;
    fo.w = (o[i * 4 + 3] - mean2) * rstd2 * sv.w + bv.w;
    *(float4*)&out[base + i * 4] = fo;
  }
}

// ------------------------------------------------------------------ launch
extern "C" void kernel_launch(void* const* d_in, const int* in_sizes, int n_in,
                              void* d_out, int out_size, void* d_ws, size_t ws_size,
                              hipStream_t stream) {
  (void)in_sizes; (void)n_in; (void)out_size; (void)ws_size;
  const float* x   = (const float*)d_in[0];
  const float* msk = (const float*)d_in[1];
  const float* wq  = (const float*)d_in[2];
  const float* wk  = (const float*)d_in[3];
  const float* wv  = (const float*)d_in[4];
  const float* w1  = (const float*)d_in[5];
  const float* b1  = (const float*)d_in[6];
  const float* w2  = (const float*)d_in[7];
  const float* b2  = (const float*)d_in[8];
  const float* l1s = (const float*)d_in[9];
  const float* l1b = (const float*)d_in[10];
  const float* l2s = (const float*)d_in[11];
  const float* l2b = (const float*)d_in[12];
  const float* l3s = (const float*)d_in[13];
  const float* l3b = (const float*)d_in[14];
  float* outp = (float*)d_out;

  char* ws = (char*)d_ws;
  unsigned short* xb   = (unsigned short*)(ws);                       // 8 MB (live thru ln_res)
  unsigned short* wt   = (unsigned short*)(ws + ((size_t)8  << 20));  // 10 MB
  unsigned short* Qb   = (unsigned short*)(ws + ((size_t)18 << 20));  // 8 MB [B,H,T,DH]
  unsigned short* Kb   = (unsigned short*)(ws + ((size_t)26 << 20));  // 8 MB
  _Float16*       Vtg  = (_Float16*)(ws + ((size_t)34 << 20));        // 8 MB k-shuffled V^T
  unsigned short* attn = (unsigned short*)(ws + ((size_t)42 << 20));  // 8 MB bf16 [B,T,D]
  unsigned short* h1b  = (unsigned short*)(ws + ((size_t)18 << 20));  // reuse Qb (8 MB bf16)
  unsigned short* gb   = (unsigned short*)(ws + ((size_t)26 << 20));  // reuse Kb
  unsigned short* ffnb = (unsigned short*)(ws + ((size_t)34 << 20));  // reuse Vtg (8 MB bf16)

  prep_kernel<<<1024 + 1280, 256, 0, stream>>>((const float4*)x, xb,
                                               wq, wk, wv, w1, w2, wt);
  gemm_qkv<<<dim3(24, 32), 256, 0, stream>>>(xb, wt, Qb, Kb, Vtg);
  flash_attn<<<512, 512, 0, stream>>>(Qb, Kb, Vtg, msk, attn);
  ln_res_kernel<<<1024, 256, 0, stream>>>(xb, attn, l1s, l1b, h1b);
  gemm_ffn<1><<<dim3(8, 64), 256, 0, stream>>>(h1b, wt + (size_t)3 * 1024 * 1024, gb, b1);
  gemm_ffn<2><<<dim3(8, 64), 256, 0, stream>>>(gb, wt + (size_t)4 * 1024 * 1024, ffnb, b2);
  ln_double_kernel<<<1024, 256, 0, stream>>>(h1b, ffnb, l2s, l2b, l3s, l3b, outp);
}